// Round 1
// baseline (1030.215 us; speedup 1.0000x reference)
//
#include <hip/hip_runtime.h>
#include <math.h>

// Problem constants (from reference)
#define KK     500   // info bits
#define MM     500   // parity checks
#define NNODES 1000  // N = K + M variable nodes
#define NSYM   250   // N / BPS
#define NITERS 5
#define MAXCDEG 24   // check-node degree cap (mean 4, Poisson(3)+1; 24 is ~impossible to exceed)
#define MAXVDEG 8    // var-node degree cap (rows of P have exactly 3 ones; parity vars have 1)

// ---------------- bit packing ----------------
__global__ void k_pack_P(const int* __restrict__ P, unsigned* __restrict__ Ppack) {
  int id = blockIdx.x * blockDim.x + threadIdx.x;
  if (id >= MM * 16) return;
  int j = id >> 4, w = id & 15;
  unsigned word = 0u;
  int base = w * 32;
  for (int bit = 0; bit < 32; ++bit) {
    int i = base + bit;
    if (i < KK && P[i * MM + j] != 0) word |= (1u << bit);
  }
  Ppack[j * 16 + w] = word;
}

__global__ void k_pack_b(const int* __restrict__ b, unsigned* __restrict__ bpack, int ncw) {
  int id = blockIdx.x * blockDim.x + threadIdx.x;
  if (id >= ncw * 16) return;
  int cw = id >> 4, w = id & 15;
  unsigned word = 0u;
  int base = w * 32;
  for (int bit = 0; bit < 32; ++bit) {
    int i = base + bit;
    if (i < KK && b[cw * KK + i] != 0) word |= (1u << bit);
  }
  bpack[cw * 16 + w] = word;
}

// ---------------- symbol indices (encode + map) ----------------
__global__ void k_sym(const unsigned* __restrict__ bpack, const unsigned* __restrict__ Ppack,
                      int* __restrict__ symidx, int ncw) {
  int id = blockIdx.x * blockDim.x + threadIdx.x;
  if (id >= ncw * NSYM) return;
  int cw = id / NSYM, s = id - cw * NSYM;
  int idx = 0;
  #pragma unroll
  for (int k = 0; k < 4; ++k) {
    int n = 4 * s + k;
    int bit;
    if (n < KK) {
      bit = (bpack[cw * 16 + (n >> 5)] >> (n & 31)) & 1;
    } else {
      int j = n - KK;
      int cnt = 0;
      #pragma unroll
      for (int w = 0; w < 16; ++w) cnt += __popc(bpack[cw * 16 + w] & Ppack[j * 16 + w]);
      bit = cnt & 1;
    }
    idx = (idx << 1) | bit;  // MSB-first: weights 8,4,2,1
  }
  symidx[id] = idx;
}

// ---------------- output 0: bf = float(b) ----------------
__global__ void k_bf(const int* __restrict__ b, float* __restrict__ out, int n) {
  int id = blockIdx.x * blockDim.x + threadIdx.x;
  if (id < n) out[id] = (float)b[id];
}

// ---------------- CSR build (deterministic, edge-index order) ----------------
__global__ void k_csr(const int* __restrict__ cn, const int* __restrict__ vn, int E,
                      int* __restrict__ cdeg, int* __restrict__ clist,
                      int* __restrict__ vdeg, int* __restrict__ vlist) {
  int id = blockIdx.x * blockDim.x + threadIdx.x;
  if (id < MM) {
    int d = 0;
    for (int e = 0; e < E; ++e)
      if (cn[e] == id && d < MAXCDEG) clist[id * MAXCDEG + d++] = e;
    cdeg[id] = d;
  } else if (id < MM + NNODES) {
    int n = id - MM;
    int d = 0;
    for (int e = 0; e < E; ++e)
      if (vn[e] == n && d < MAXVDEG) vlist[n * MAXVDEG + d++] = e;
    vdeg[n] = d;
  }
}

// ---------------- 16-QAM constellation point ----------------
__device__ __forceinline__ void qam_point(int p, double& re, double& im) {
  const double s = 0.31622776601683794;  // 1/sqrt(10)
  int b0 = (p >> 3) & 1, b1 = (p >> 2) & 1, b2 = (p >> 1) & 1, b3 = p & 1;
  re = (double)((1 - 2 * b0) * (2 - (1 - 2 * b2))) * s;
  im = (double)((1 - 2 * b1) * (2 - (1 - 2 * b3))) * s;
}

// ---------------- channel + LMMSE + max-log LLR (per symbol time t) ----------------
__global__ void k_lmmse(const float* __restrict__ h_re, const float* __restrict__ h_im,
                        const float* __restrict__ n_re, const float* __restrict__ n_im,
                        const float* __restrict__ ebno, const int* __restrict__ symidx,
                        double* __restrict__ Lch, int T, int ncw) {
  int t = blockIdx.x * blockDim.x + threadIdx.x;
  if (t >= T) return;
  int bt = t / NSYM, s = t - bt * NSYM;

  double no = 1.0 / (pow(10.0, (double)ebno[0] * 0.1) * 2.0);  // BPS*RATE = 2
  const double is2 = 0.7071067811865475244;                     // 1/sqrt(2)

  double Hr[4][4], Hi[4][4];
  #pragma unroll
  for (int i = 0; i < 4; ++i)
    #pragma unroll
    for (int j = 0; j < 4; ++j) {
      Hr[i][j] = (double)h_re[t * 16 + i * 4 + j] * is2;
      Hi[i][j] = (double)h_im[t * 16 + i * 4 + j] * is2;
    }

  // transmitted symbols x_f[t][j]  (j = UE)
  double xr[4], xi[4];
  #pragma unroll
  for (int j = 0; j < 4; ++j) {
    int p = symidx[(bt * 4 + j) * NSYM + s];
    qam_point(p, xr[j], xi[j]);
  }

  // y = H x + w
  double sq = sqrt(no * 0.5);
  double yr[4], yi[4];
  #pragma unroll
  for (int i = 0; i < 4; ++i) {
    double ar = (double)n_re[t * 4 + i] * sq;
    double ai = (double)n_im[t * 4 + i] * sq;
    #pragma unroll
    for (int j = 0; j < 4; ++j) {
      ar += Hr[i][j] * xr[j] - Hi[i][j] * xi[j];
      ai += Hr[i][j] * xi[j] + Hi[i][j] * xr[j];
    }
    yr[i] = ar; yi[i] = ai;
  }

  // A = H H^H + no I  (lower triangle), then Cholesky A = L L^H in place
  double Lr[4][4], Li[4][4];
  #pragma unroll
  for (int i = 0; i < 4; ++i)
    #pragma unroll
    for (int j = 0; j < 4; ++j) { Lr[i][j] = 0.0; Li[i][j] = 0.0; }
  #pragma unroll
  for (int i = 0; i < 4; ++i)
    #pragma unroll
    for (int j = 0; j < 4; ++j) {
      if (j <= i) {
        double ar = 0.0, ai = 0.0;
        #pragma unroll
        for (int k = 0; k < 4; ++k) {
          ar += Hr[i][k] * Hr[j][k] + Hi[i][k] * Hi[j][k];
          ai += Hi[i][k] * Hr[j][k] - Hr[i][k] * Hi[j][k];
        }
        Lr[i][j] = ar; Li[i][j] = ai;
      }
    }
  #pragma unroll
  for (int i = 0; i < 4; ++i) Lr[i][i] += no;

  #pragma unroll
  for (int j = 0; j < 4; ++j) {
    double d = Lr[j][j];
    #pragma unroll
    for (int k = 0; k < j; ++k) d -= Lr[j][k] * Lr[j][k] + Li[j][k] * Li[j][k];
    d = sqrt(d);
    Lr[j][j] = d;
    double inv = 1.0 / d;
    #pragma unroll
    for (int i = j + 1; i < 4; ++i) {
      double cr = Lr[i][j], ci = Li[i][j];
      #pragma unroll
      for (int k = 0; k < j; ++k) {
        cr -= Lr[i][k] * Lr[j][k] + Li[i][k] * Li[j][k];
        ci -= Li[i][k] * Lr[j][k] - Lr[i][k] * Li[j][k];
      }
      Lr[i][j] = cr * inv; Li[i][j] = ci * inv;
    }
  }

  // forward solve: U = L^{-1} H (in place on H), v = L^{-1} y (in place on y)
  #pragma unroll
  for (int i = 0; i < 4; ++i) {
    double inv = 1.0 / Lr[i][i];
    #pragma unroll
    for (int j = 0; j < 4; ++j) {
      double ur = Hr[i][j], ui = Hi[i][j];
      #pragma unroll
      for (int k = 0; k < i; ++k) {
        ur -= Lr[i][k] * Hr[k][j] - Li[i][k] * Hi[k][j];
        ui -= Lr[i][k] * Hi[k][j] + Li[i][k] * Hr[k][j];
      }
      Hr[i][j] = ur * inv; Hi[i][j] = ui * inv;
    }
    double vr = yr[i], vi = yi[i];
    #pragma unroll
    for (int k = 0; k < i; ++k) {
      vr -= Lr[i][k] * yr[k] - Li[i][k] * yi[k];
      vi -= Lr[i][k] * yi[k] + Li[i][k] * yr[k];
    }
    yr[i] = vr * inv; yi[i] = vi * inv;
  }

  // per-UE: x_raw = U^H v, d_j = ||U[:,j]||^2, then max-log LLRs
  #pragma unroll
  for (int j = 0; j < 4; ++j) {
    double dj = 0.0, rr = 0.0, ri = 0.0;
    #pragma unroll
    for (int i = 0; i < 4; ++i) {
      dj += Hr[i][j] * Hr[i][j] + Hi[i][j] * Hi[i][j];
      rr += Hr[i][j] * yr[i] + Hi[i][j] * yi[i];
      ri += Hr[i][j] * yi[i] - Hi[i][j] * yr[i];
    }
    double xh_r = rr / dj, xh_i = ri / dj;
    double noe = fmax(1.0 / dj - 1.0, 1e-12);

    double m0[4] = {-1e30, -1e30, -1e30, -1e30};
    double m1[4] = {-1e30, -1e30, -1e30, -1e30};
    #pragma unroll
    for (int p = 0; p < 16; ++p) {
      double pr, pi;
      qam_point(p, pr, pi);
      double dr = xh_r - pr, di = xh_i - pi;
      double met = -(dr * dr + di * di) / noe;
      #pragma unroll
      for (int k = 0; k < 4; ++k) {
        if ((p >> (3 - k)) & 1) m1[k] = fmax(m1[k], met);
        else                    m0[k] = fmax(m0[k], met);
      }
    }
    int cw = bt * 4 + j;
    #pragma unroll
    for (int k = 0; k < 4; ++k)
      Lch[(size_t)(s * 4 + k) * ncw + cw] = m0[k] - m1[k];
  }
}

// ---------------- BP decoder ----------------
__global__ void k_vtot(const double* __restrict__ Lch, const double* __restrict__ c2v,
                       const int* __restrict__ vdeg, const int* __restrict__ vlist,
                       double* __restrict__ vtot, int ncw) {
  int cw = blockIdx.x * blockDim.x + threadIdx.x;
  int n = blockIdx.y;
  if (cw >= ncw) return;
  double acc = Lch[(size_t)n * ncw + cw];
  int d = vdeg[n];
  for (int k = 0; k < d; ++k)
    acc += c2v[(size_t)vlist[n * MAXVDEG + k] * ncw + cw];
  vtot[(size_t)n * ncw + cw] = acc;
}

__global__ void k_check(const double* __restrict__ vtot, const int* __restrict__ vn,
                        const int* __restrict__ cdeg, const int* __restrict__ clist,
                        double* __restrict__ c2v, int ncw) {
  int cw = blockIdx.x * blockDim.x + threadIdx.x;
  int j = blockIdx.y;
  if (cw >= ncw) return;
  int d = cdeg[j];
  double tt[MAXCDEG];
  double prod = 1.0;
  #pragma unroll
  for (int k = 0; k < MAXCDEG; ++k) {
    if (k < d) {
      int e = clist[j * MAXCDEG + k];
      double m = vtot[(size_t)vn[e] * ncw + cw] - c2v[(size_t)e * ncw + cw];
      double x = m * 0.5;
      x = fmin(fmax(x, -9.9), 9.9);
      double tv = tanh(x);
      tv = (tv >= 0.0) ? fmax(tv, 1e-7) : fmin(tv, -1e-7);
      tt[k] = tv;
      prod *= tv;
    }
  }
  #pragma unroll
  for (int k = 0; k < MAXCDEG; ++k) {
    if (k < d) {
      int e = clist[j * MAXCDEG + k];
      double r = prod / tt[k];
      r = fmin(fmax(r, -0.999999), 0.999999);
      c2v[(size_t)e * ncw + cw] = 2.0 * atanh(r);
    }
  }
}

__global__ void k_decide(const double* __restrict__ Lch, const double* __restrict__ c2v,
                         const int* __restrict__ vdeg, const int* __restrict__ vlist,
                         float* __restrict__ out, int ncw) {
  int cw = blockIdx.x * blockDim.x + threadIdx.x;
  int n = blockIdx.y;  // n < KK
  if (cw >= ncw) return;
  double acc = Lch[(size_t)n * ncw + cw];
  int d = vdeg[n];
  for (int k = 0; k < d; ++k)
    acc += c2v[(size_t)vlist[n * MAXVDEG + k] * ncw + cw];
  out[(size_t)ncw * KK + (size_t)cw * KK + n] = (acc < 0.0) ? 1.0f : 0.0f;
}

// ---------------- launcher ----------------
extern "C" void kernel_launch(void* const* d_in, const int* in_sizes, int n_in,
                              void* d_out, int out_size, void* d_ws, size_t ws_size,
                              hipStream_t stream) {
  const float* ebno = (const float*)d_in[1];
  const int*   b    = (const int*)d_in[2];
  const int*   P    = (const int*)d_in[3];
  const int*   cn   = (const int*)d_in[4];
  const int*   vn   = (const int*)d_in[5];
  const float* h_re = (const float*)d_in[6];
  const float* h_im = (const float*)d_in[7];
  const float* nre  = (const float*)d_in[8];
  const float* nim  = (const float*)d_in[9];
  float* out = (float*)d_out;

  int E     = in_sizes[4];
  int batch = in_sizes[2] / (4 * KK);
  int ncw   = batch * 4;
  int T     = batch * NSYM;

  char* ws = (char*)d_ws;
  size_t off = 0;
  auto alloc = [&](size_t bytes) -> void* {
    void* p = ws + off;
    off += (bytes + 255) & ~(size_t)255;
    return p;
  };
  double*   Lch    = (double*)alloc((size_t)NNODES * ncw * 8);
  double*   c2v    = (double*)alloc((size_t)E * ncw * 8);
  double*   vtot   = (double*)alloc((size_t)NNODES * ncw * 8);
  int*      symidx = (int*)alloc((size_t)ncw * NSYM * 4);
  unsigned* Ppack  = (unsigned*)alloc((size_t)MM * 16 * 4);
  unsigned* bpack  = (unsigned*)alloc((size_t)ncw * 16 * 4);
  int*      cdeg   = (int*)alloc((size_t)MM * 4);
  int*      clist  = (int*)alloc((size_t)MM * MAXCDEG * 4);
  int*      vdeg   = (int*)alloc((size_t)NNODES * 4);
  int*      vlist  = (int*)alloc((size_t)NNODES * MAXVDEG * 4);
  (void)ws_size; (void)n_in; (void)out_size;

  const int tb = 256;
  k_pack_P<<<dim3((MM * 16 + tb - 1) / tb), dim3(tb), 0, stream>>>(P, Ppack);
  k_pack_b<<<dim3((ncw * 16 + tb - 1) / tb), dim3(tb), 0, stream>>>(b, bpack, ncw);
  k_sym<<<dim3((ncw * NSYM + tb - 1) / tb), dim3(tb), 0, stream>>>(bpack, Ppack, symidx, ncw);
  k_bf<<<dim3((ncw * KK + tb - 1) / tb), dim3(tb), 0, stream>>>(b, out, ncw * KK);
  k_csr<<<dim3((MM + NNODES + tb - 1) / tb), dim3(tb), 0, stream>>>(cn, vn, E, cdeg, clist, vdeg, vlist);
  k_lmmse<<<dim3((T + tb - 1) / tb), dim3(tb), 0, stream>>>(h_re, h_im, nre, nim, ebno, symidx, Lch, T, ncw);

  hipMemsetAsync(c2v, 0, (size_t)E * ncw * 8, stream);

  int cwb = (ncw + tb - 1) / tb;
  for (int it = 0; it < NITERS; ++it) {
    k_vtot<<<dim3(cwb, NNODES), dim3(tb), 0, stream>>>(Lch, c2v, vdeg, vlist, vtot, ncw);
    k_check<<<dim3(cwb, MM), dim3(tb), 0, stream>>>(vtot, vn, cdeg, clist, c2v, ncw);
  }
  k_decide<<<dim3(cwb, KK), dim3(tb), 0, stream>>>(Lch, c2v, vdeg, vlist, out, ncw);
}

// Round 2
// 830.551 us; speedup vs baseline: 1.2404x; 1.2404x over previous
//
#include <hip/hip_runtime.h>
#include <math.h>

// Problem constants (from reference)
#define KK     500   // info bits
#define MM     500   // parity checks
#define NNODES 1000  // N = K + M variable nodes
#define NSYM   250   // N / BPS
#define NITERS 5
#define MAXCDEG 24   // check-node degree cap (col deg ~Poisson(3)+1)
#define MAXVDEG 8    // var-node degree cap (info vars deg 3, parity vars deg 1)

// ---------------- bit packing ----------------
__global__ void k_pack_P(const int* __restrict__ P, unsigned* __restrict__ Ppack) {
  int id = blockIdx.x * blockDim.x + threadIdx.x;
  if (id >= MM * 16) return;
  int j = id >> 4, w = id & 15;
  unsigned word = 0u;
  int base = w * 32;
  for (int bit = 0; bit < 32; ++bit) {
    int i = base + bit;
    if (i < KK && P[i * MM + j] != 0) word |= (1u << bit);
  }
  Ppack[j * 16 + w] = word;
}

__global__ void k_pack_b(const int* __restrict__ b, unsigned* __restrict__ bpack, int ncw) {
  int id = blockIdx.x * blockDim.x + threadIdx.x;
  if (id >= ncw * 16) return;
  int cw = id >> 4, w = id & 15;
  unsigned word = 0u;
  int base = w * 32;
  for (int bit = 0; bit < 32; ++bit) {
    int i = base + bit;
    if (i < KK && b[cw * KK + i] != 0) word |= (1u << bit);
  }
  bpack[cw * 16 + w] = word;
}

// ---------------- symbol indices (encode + map) ----------------
__global__ void k_sym(const unsigned* __restrict__ bpack, const unsigned* __restrict__ Ppack,
                      int* __restrict__ symidx, int ncw) {
  int id = blockIdx.x * blockDim.x + threadIdx.x;
  if (id >= ncw * NSYM) return;
  int cw = id / NSYM, s = id - cw * NSYM;
  int idx = 0;
  #pragma unroll
  for (int k = 0; k < 4; ++k) {
    int n = 4 * s + k;
    int bit;
    if (n < KK) {
      bit = (bpack[cw * 16 + (n >> 5)] >> (n & 31)) & 1;
    } else {
      int j = n - KK;
      int cnt = 0;
      #pragma unroll
      for (int w = 0; w < 16; ++w) cnt += __popc(bpack[cw * 16 + w] & Ppack[j * 16 + w]);
      bit = cnt & 1;
    }
    idx = (idx << 1) | bit;  // MSB-first: weights 8,4,2,1
  }
  symidx[id] = idx;
}

// ---------------- output 0: bf = float(b) ----------------
__global__ void k_bf(const int* __restrict__ b, float* __restrict__ out, int n) {
  int id = blockIdx.x * blockDim.x + threadIdx.x;
  if (id < n) out[id] = (float)b[id];
}

// ---------------- CSR build: one thread per edge, atomic slot claim ------
// Slot order within a node list is nondeterministic; lists are consumed as
// sets (sum / product over edges) so only last-bit rounding can differ.
__global__ void k_fill(const int* __restrict__ cn, const int* __restrict__ vn, int E,
                       int* __restrict__ cdeg, int* __restrict__ clist,
                       int* __restrict__ vdeg, int* __restrict__ vlist) {
  int e = blockIdx.x * blockDim.x + threadIdx.x;
  if (e >= E) return;
  int j = cn[e];
  int s = atomicAdd(&cdeg[j], 1);
  if (s < MAXCDEG) clist[j * MAXCDEG + s] = e;
  int n = vn[e];
  int t = atomicAdd(&vdeg[n], 1);
  if (t < MAXVDEG) vlist[n * MAXVDEG + t] = e;
}

// ---------------- 16-QAM constellation point ----------------
__device__ __forceinline__ void qam_point(int p, double& re, double& im) {
  const double s = 0.31622776601683794;  // 1/sqrt(10)
  int b0 = (p >> 3) & 1, b1 = (p >> 2) & 1, b2 = (p >> 1) & 1, b3 = p & 1;
  re = (double)((1 - 2 * b0) * (2 - (1 - 2 * b2))) * s;
  im = (double)((1 - 2 * b1) * (2 - (1 - 2 * b3))) * s;
}

// ---------------- channel + LMMSE + max-log LLR (per symbol time t) ----------------
__global__ void k_lmmse(const float* __restrict__ h_re, const float* __restrict__ h_im,
                        const float* __restrict__ n_re, const float* __restrict__ n_im,
                        const float* __restrict__ ebno, const int* __restrict__ symidx,
                        double* __restrict__ Lch, int T, int ncw) {
  int t = blockIdx.x * blockDim.x + threadIdx.x;
  if (t >= T) return;
  int bt = t / NSYM, s = t - bt * NSYM;

  double no = 1.0 / (pow(10.0, (double)ebno[0] * 0.1) * 2.0);  // BPS*RATE = 2
  const double is2 = 0.7071067811865475244;                     // 1/sqrt(2)

  double Hr[4][4], Hi[4][4];
  #pragma unroll
  for (int i = 0; i < 4; ++i)
    #pragma unroll
    for (int j = 0; j < 4; ++j) {
      Hr[i][j] = (double)h_re[t * 16 + i * 4 + j] * is2;
      Hi[i][j] = (double)h_im[t * 16 + i * 4 + j] * is2;
    }

  // transmitted symbols x_f[t][j]  (j = UE)
  double xr[4], xi[4];
  #pragma unroll
  for (int j = 0; j < 4; ++j) {
    int p = symidx[(bt * 4 + j) * NSYM + s];
    qam_point(p, xr[j], xi[j]);
  }

  // y = H x + w
  double sq = sqrt(no * 0.5);
  double yr[4], yi[4];
  #pragma unroll
  for (int i = 0; i < 4; ++i) {
    double ar = (double)n_re[t * 4 + i] * sq;
    double ai = (double)n_im[t * 4 + i] * sq;
    #pragma unroll
    for (int j = 0; j < 4; ++j) {
      ar += Hr[i][j] * xr[j] - Hi[i][j] * xi[j];
      ai += Hr[i][j] * xi[j] + Hi[i][j] * xr[j];
    }
    yr[i] = ar; yi[i] = ai;
  }

  // A = H H^H + no I  (lower triangle), then Cholesky A = L L^H in place
  double Lr[4][4], Li[4][4];
  #pragma unroll
  for (int i = 0; i < 4; ++i)
    #pragma unroll
    for (int j = 0; j < 4; ++j) { Lr[i][j] = 0.0; Li[i][j] = 0.0; }
  #pragma unroll
  for (int i = 0; i < 4; ++i)
    #pragma unroll
    for (int j = 0; j < 4; ++j) {
      if (j <= i) {
        double ar = 0.0, ai = 0.0;
        #pragma unroll
        for (int k = 0; k < 4; ++k) {
          ar += Hr[i][k] * Hr[j][k] + Hi[i][k] * Hi[j][k];
          ai += Hi[i][k] * Hr[j][k] - Hr[i][k] * Hi[j][k];
        }
        Lr[i][j] = ar; Li[i][j] = ai;
      }
    }
  #pragma unroll
  for (int i = 0; i < 4; ++i) Lr[i][i] += no;

  #pragma unroll
  for (int j = 0; j < 4; ++j) {
    double d = Lr[j][j];
    #pragma unroll
    for (int k = 0; k < j; ++k) d -= Lr[j][k] * Lr[j][k] + Li[j][k] * Li[j][k];
    d = sqrt(d);
    Lr[j][j] = d;
    double inv = 1.0 / d;
    #pragma unroll
    for (int i = j + 1; i < 4; ++i) {
      double cr = Lr[i][j], ci = Li[i][j];
      #pragma unroll
      for (int k = 0; k < j; ++k) {
        cr -= Lr[i][k] * Lr[j][k] + Li[i][k] * Li[j][k];
        ci -= Li[i][k] * Lr[j][k] - Lr[i][k] * Li[j][k];
      }
      Lr[i][j] = cr * inv; Li[i][j] = ci * inv;
    }
  }

  // forward solve: U = L^{-1} H (in place on H), v = L^{-1} y (in place on y)
  #pragma unroll
  for (int i = 0; i < 4; ++i) {
    double inv = 1.0 / Lr[i][i];
    #pragma unroll
    for (int j = 0; j < 4; ++j) {
      double ur = Hr[i][j], ui = Hi[i][j];
      #pragma unroll
      for (int k = 0; k < i; ++k) {
        ur -= Lr[i][k] * Hr[k][j] - Li[i][k] * Hi[k][j];
        ui -= Lr[i][k] * Hi[k][j] + Li[i][k] * Hr[k][j];
      }
      Hr[i][j] = ur * inv; Hi[i][j] = ui * inv;
    }
    double vr = yr[i], vi = yi[i];
    #pragma unroll
    for (int k = 0; k < i; ++k) {
      vr -= Lr[i][k] * yr[k] - Li[i][k] * yi[k];
      vi -= Lr[i][k] * yi[k] + Li[i][k] * yr[k];
    }
    yr[i] = vr * inv; yi[i] = vi * inv;
  }

  // per-UE: x_raw = U^H v, d_j = ||U[:,j]||^2, then max-log LLRs
  #pragma unroll
  for (int j = 0; j < 4; ++j) {
    double dj = 0.0, rr = 0.0, ri = 0.0;
    #pragma unroll
    for (int i = 0; i < 4; ++i) {
      dj += Hr[i][j] * Hr[i][j] + Hi[i][j] * Hi[i][j];
      rr += Hr[i][j] * yr[i] + Hi[i][j] * yi[i];
      ri += Hr[i][j] * yi[i] - Hi[i][j] * yr[i];
    }
    double xh_r = rr / dj, xh_i = ri / dj;
    double noe = fmax(1.0 / dj - 1.0, 1e-12);

    double m0[4] = {-1e30, -1e30, -1e30, -1e30};
    double m1[4] = {-1e30, -1e30, -1e30, -1e30};
    #pragma unroll
    for (int p = 0; p < 16; ++p) {
      double pr, pi;
      qam_point(p, pr, pi);
      double dr = xh_r - pr, di = xh_i - pi;
      double met = -(dr * dr + di * di) / noe;
      #pragma unroll
      for (int k = 0; k < 4; ++k) {
        if ((p >> (3 - k)) & 1) m1[k] = fmax(m1[k], met);
        else                    m0[k] = fmax(m0[k], met);
      }
    }
    int cw = bt * 4 + j;
    #pragma unroll
    for (int k = 0; k < 4; ++k)
      Lch[(size_t)(s * 4 + k) * ncw + cw] = m0[k] - m1[k];
  }
}

// ---------------- BP decoder ----------------
__global__ void k_vtot(const double* __restrict__ Lch, const double* __restrict__ c2v,
                       const int* __restrict__ vdeg, const int* __restrict__ vlist,
                       double* __restrict__ vtot, int ncw) {
  int cw = blockIdx.x * blockDim.x + threadIdx.x;
  int n = blockIdx.y;
  if (cw >= ncw) return;
  double acc = Lch[(size_t)n * ncw + cw];
  int d = vdeg[n];
  for (int k = 0; k < d; ++k)
    acc += c2v[(size_t)vlist[n * MAXVDEG + k] * ncw + cw];
  vtot[(size_t)n * ncw + cw] = acc;
}

__global__ void k_check(const double* __restrict__ vtot, const int* __restrict__ vn,
                        const int* __restrict__ cdeg, const int* __restrict__ clist,
                        double* __restrict__ c2v, int ncw) {
  int cw = blockIdx.x * blockDim.x + threadIdx.x;
  int j = blockIdx.y;
  if (cw >= ncw) return;
  int d = cdeg[j];
  double tt[MAXCDEG];
  double prod = 1.0;
  #pragma unroll
  for (int k = 0; k < MAXCDEG; ++k) {
    if (k < d) {
      int e = clist[j * MAXCDEG + k];
      double m = vtot[(size_t)vn[e] * ncw + cw] - c2v[(size_t)e * ncw + cw];
      double x = m * 0.5;
      x = fmin(fmax(x, -9.9), 9.9);
      double tv = tanh(x);
      tv = (tv >= 0.0) ? fmax(tv, 1e-7) : fmin(tv, -1e-7);
      tt[k] = tv;
      prod *= tv;
    }
  }
  #pragma unroll
  for (int k = 0; k < MAXCDEG; ++k) {
    if (k < d) {
      int e = clist[j * MAXCDEG + k];
      double r = prod / tt[k];
      r = fmin(fmax(r, -0.999999), 0.999999);
      c2v[(size_t)e * ncw + cw] = 2.0 * atanh(r);
    }
  }
}

// iteration 0: c2v == 0 everywhere, so vtot == Lch and m_vc == Lch.
// Reads Lch directly; writes all E*ncw c2v entries (so no memset needed).
__global__ void k_check0(const double* __restrict__ Lch, const int* __restrict__ vn,
                         const int* __restrict__ cdeg, const int* __restrict__ clist,
                         double* __restrict__ c2v, int ncw) {
  int cw = blockIdx.x * blockDim.x + threadIdx.x;
  int j = blockIdx.y;
  if (cw >= ncw) return;
  int d = cdeg[j];
  double tt[MAXCDEG];
  double prod = 1.0;
  #pragma unroll
  for (int k = 0; k < MAXCDEG; ++k) {
    if (k < d) {
      int e = clist[j * MAXCDEG + k];
      double m = Lch[(size_t)vn[e] * ncw + cw];
      double x = m * 0.5;
      x = fmin(fmax(x, -9.9), 9.9);
      double tv = tanh(x);
      tv = (tv >= 0.0) ? fmax(tv, 1e-7) : fmin(tv, -1e-7);
      tt[k] = tv;
      prod *= tv;
    }
  }
  #pragma unroll
  for (int k = 0; k < MAXCDEG; ++k) {
    if (k < d) {
      int e = clist[j * MAXCDEG + k];
      double r = prod / tt[k];
      r = fmin(fmax(r, -0.999999), 0.999999);
      c2v[(size_t)e * ncw + cw] = 2.0 * atanh(r);
    }
  }
}

__global__ void k_decide(const double* __restrict__ Lch, const double* __restrict__ c2v,
                         const int* __restrict__ vdeg, const int* __restrict__ vlist,
                         float* __restrict__ out, int ncw) {
  int cw = blockIdx.x * blockDim.x + threadIdx.x;
  int n = blockIdx.y;  // n < KK
  if (cw >= ncw) return;
  double acc = Lch[(size_t)n * ncw + cw];
  int d = vdeg[n];
  for (int k = 0; k < d; ++k)
    acc += c2v[(size_t)vlist[n * MAXVDEG + k] * ncw + cw];
  out[(size_t)ncw * KK + (size_t)cw * KK + n] = (acc < 0.0) ? 1.0f : 0.0f;
}

// ---------------- launcher ----------------
extern "C" void kernel_launch(void* const* d_in, const int* in_sizes, int n_in,
                              void* d_out, int out_size, void* d_ws, size_t ws_size,
                              hipStream_t stream) {
  const float* ebno = (const float*)d_in[1];
  const int*   b    = (const int*)d_in[2];
  const int*   P    = (const int*)d_in[3];
  const int*   cn   = (const int*)d_in[4];
  const int*   vn   = (const int*)d_in[5];
  const float* h_re = (const float*)d_in[6];
  const float* h_im = (const float*)d_in[7];
  const float* nre  = (const float*)d_in[8];
  const float* nim  = (const float*)d_in[9];
  float* out = (float*)d_out;

  int E     = in_sizes[4];
  int batch = in_sizes[2] / (4 * KK);
  int ncw   = batch * 4;
  int T     = batch * NSYM;

  char* ws = (char*)d_ws;
  size_t off = 0;
  auto alloc = [&](size_t bytes) -> void* {
    void* p = ws + off;
    off += (bytes + 255) & ~(size_t)255;
    return p;
  };
  double*   Lch    = (double*)alloc((size_t)NNODES * ncw * 8);
  double*   c2v    = (double*)alloc((size_t)E * ncw * 8);
  double*   vtot   = (double*)alloc((size_t)NNODES * ncw * 8);
  int*      symidx = (int*)alloc((size_t)ncw * NSYM * 4);
  unsigned* Ppack  = (unsigned*)alloc((size_t)MM * 16 * 4);
  unsigned* bpack  = (unsigned*)alloc((size_t)ncw * 16 * 4);
  int*      cdeg   = (int*)alloc((size_t)MM * 4);
  int*      clist  = (int*)alloc((size_t)MM * MAXCDEG * 4);
  int*      vdeg   = (int*)alloc((size_t)NNODES * 4);
  int*      vlist  = (int*)alloc((size_t)NNODES * MAXVDEG * 4);
  (void)ws_size; (void)n_in; (void)out_size;

  const int tb = 256;
  // degree counters must start at zero (ws is poisoned before every call)
  hipMemsetAsync(cdeg, 0, (size_t)MM * 4, stream);
  hipMemsetAsync(vdeg, 0, (size_t)NNODES * 4, stream);

  k_pack_P<<<dim3((MM * 16 + tb - 1) / tb), dim3(tb), 0, stream>>>(P, Ppack);
  k_pack_b<<<dim3((ncw * 16 + tb - 1) / tb), dim3(tb), 0, stream>>>(b, bpack, ncw);
  k_sym<<<dim3((ncw * NSYM + tb - 1) / tb), dim3(tb), 0, stream>>>(bpack, Ppack, symidx, ncw);
  k_bf<<<dim3((ncw * KK + tb - 1) / tb), dim3(tb), 0, stream>>>(b, out, ncw * KK);
  k_fill<<<dim3((E + tb - 1) / tb), dim3(tb), 0, stream>>>(cn, vn, E, cdeg, clist, vdeg, vlist);
  k_lmmse<<<dim3((T + tb - 1) / tb), dim3(tb), 0, stream>>>(h_re, h_im, nre, nim, ebno, symidx, Lch, T, ncw);

  int cwb = (ncw + tb - 1) / tb;
  // iteration 0 specialized (c2v == 0): no memset, no vtot pass
  k_check0<<<dim3(cwb, MM), dim3(tb), 0, stream>>>(Lch, vn, cdeg, clist, c2v, ncw);
  for (int it = 1; it < NITERS; ++it) {
    k_vtot<<<dim3(cwb, NNODES), dim3(tb), 0, stream>>>(Lch, c2v, vdeg, vlist, vtot, ncw);
    k_check<<<dim3(cwb, MM), dim3(tb), 0, stream>>>(vtot, vn, cdeg, clist, c2v, ncw);
  }
  k_decide<<<dim3(cwb, KK), dim3(tb), 0, stream>>>(Lch, c2v, vdeg, vlist, out, ncw);
}

// Round 3
// 386.801 us; speedup vs baseline: 2.6634x; 2.1472x over previous
//
#include <hip/hip_runtime.h>
#include <math.h>

// Problem constants (from reference)
#define KK     500   // info bits
#define MM     500   // parity checks
#define NNODES 1000  // N = K + M variable nodes
#define NSYM   250   // N / BPS
#define NITERS 5
#define MAXCDEG 24   // check-node degree cap
#define MAXVDEG 8    // var-node degree cap

// ---------------- bit packing ----------------
__global__ void __launch_bounds__(256) k_pack_P(const int* __restrict__ P, unsigned* __restrict__ Ppack) {
  int id = blockIdx.x * blockDim.x + threadIdx.x;
  if (id >= MM * 16) return;
  int j = id >> 4, w = id & 15;
  unsigned word = 0u;
  int base = w * 32;
  for (int bit = 0; bit < 32; ++bit) {
    int i = base + bit;
    if (i < KK && P[i * MM + j] != 0) word |= (1u << bit);
  }
  Ppack[j * 16 + w] = word;
}

__global__ void __launch_bounds__(256) k_pack_b(const int* __restrict__ b, unsigned* __restrict__ bpack, int ncw) {
  int id = blockIdx.x * blockDim.x + threadIdx.x;
  if (id >= ncw * 16) return;
  int cw = id >> 4, w = id & 15;
  unsigned word = 0u;
  int base = w * 32;
  for (int bit = 0; bit < 32; ++bit) {
    int i = base + bit;
    if (i < KK && b[cw * KK + i] != 0) word |= (1u << bit);
  }
  bpack[cw * 16 + w] = word;
}

// ---------------- symbol indices (encode + map) ----------------
__global__ void __launch_bounds__(256) k_sym(const unsigned* __restrict__ bpack, const unsigned* __restrict__ Ppack,
                                             int* __restrict__ symidx, int ncw) {
  int id = blockIdx.x * blockDim.x + threadIdx.x;
  if (id >= ncw * NSYM) return;
  int cw = id / NSYM, s = id - cw * NSYM;
  int idx = 0;
  #pragma unroll
  for (int k = 0; k < 4; ++k) {
    int n = 4 * s + k;
    int bit;
    if (n < KK) {
      bit = (bpack[cw * 16 + (n >> 5)] >> (n & 31)) & 1;
    } else {
      int j = n - KK;
      int cnt = 0;
      #pragma unroll
      for (int w = 0; w < 16; ++w) cnt += __popc(bpack[cw * 16 + w] & Ppack[j * 16 + w]);
      bit = cnt & 1;
    }
    idx = (idx << 1) | bit;  // MSB-first: weights 8,4,2,1
  }
  symidx[id] = idx;
}

// ---------------- output 0: bf = float(b) ----------------
__global__ void __launch_bounds__(256) k_bf(const int* __restrict__ b, float* __restrict__ out, int n) {
  int id = blockIdx.x * blockDim.x + threadIdx.x;
  if (id < n) out[id] = (float)b[id];
}

// ---------------- CSR build: one thread per edge, atomic slot claim ------
__global__ void __launch_bounds__(256) k_fill(const int* __restrict__ cn, const int* __restrict__ vn, int E,
                                              int* __restrict__ cdeg, int* __restrict__ clist,
                                              int* __restrict__ vdeg, int* __restrict__ vlist) {
  int e = blockIdx.x * blockDim.x + threadIdx.x;
  if (e >= E) return;
  int j = cn[e];
  int s = atomicAdd(&cdeg[j], 1);
  if (s < MAXCDEG) clist[j * MAXCDEG + s] = e;
  int n = vn[e];
  int t = atomicAdd(&vdeg[n], 1);
  if (t < MAXVDEG) vlist[n * MAXVDEG + t] = e;
}

// ---------------- 16-QAM constellation point ----------------
__device__ __forceinline__ void qam_point(int p, double& re, double& im) {
  const double s = 0.31622776601683794;  // 1/sqrt(10)
  int b0 = (p >> 3) & 1, b1 = (p >> 2) & 1, b2 = (p >> 1) & 1, b3 = p & 1;
  re = (double)((1 - 2 * b0) * (2 - (1 - 2 * b2))) * s;
  im = (double)((1 - 2 * b1) * (2 - (1 - 2 * b3))) * s;
}

// ---------------- channel + LMMSE + max-log LLR (per symbol time t) --------
// fp64 throughout; __launch_bounds__(256,1) unlocks the full VGPR budget
// (round-2 profile: VGPR capped at 64 -> ~118 MB of spill scratch traffic).
__global__ void __launch_bounds__(256, 1)
k_lmmse(const float* __restrict__ h_re, const float* __restrict__ h_im,
        const float* __restrict__ n_re, const float* __restrict__ n_im,
        const float* __restrict__ ebno, const int* __restrict__ symidx,
        float* __restrict__ Lch, int T, int ncw) {
  int t = blockIdx.x * blockDim.x + threadIdx.x;
  if (t >= T) return;
  int bt = t / NSYM, s = t - bt * NSYM;

  double no = 1.0 / (pow(10.0, (double)ebno[0] * 0.1) * 2.0);  // BPS*RATE = 2
  const double is2 = 0.7071067811865475244;                     // 1/sqrt(2)

  double Hr[4][4], Hi[4][4];
  #pragma unroll
  for (int i = 0; i < 4; ++i)
    #pragma unroll
    for (int j = 0; j < 4; ++j) {
      Hr[i][j] = (double)h_re[t * 16 + i * 4 + j] * is2;
      Hi[i][j] = (double)h_im[t * 16 + i * 4 + j] * is2;
    }

  double xr[4], xi[4];
  #pragma unroll
  for (int j = 0; j < 4; ++j) {
    int p = symidx[(bt * 4 + j) * NSYM + s];
    qam_point(p, xr[j], xi[j]);
  }

  // y = H x + w
  double sq = sqrt(no * 0.5);
  double yr[4], yi[4];
  #pragma unroll
  for (int i = 0; i < 4; ++i) {
    double ar = (double)n_re[t * 4 + i] * sq;
    double ai = (double)n_im[t * 4 + i] * sq;
    #pragma unroll
    for (int j = 0; j < 4; ++j) {
      ar += Hr[i][j] * xr[j] - Hi[i][j] * xi[j];
      ai += Hr[i][j] * xi[j] + Hi[i][j] * xr[j];
    }
    yr[i] = ar; yi[i] = ai;
  }

  // A = H H^H + no I, Cholesky A = L L^H
  double Lr[4][4], Li[4][4];
  #pragma unroll
  for (int i = 0; i < 4; ++i)
    #pragma unroll
    for (int j = 0; j < 4; ++j) { Lr[i][j] = 0.0; Li[i][j] = 0.0; }
  #pragma unroll
  for (int i = 0; i < 4; ++i)
    #pragma unroll
    for (int j = 0; j < 4; ++j) {
      if (j <= i) {
        double ar = 0.0, ai = 0.0;
        #pragma unroll
        for (int k = 0; k < 4; ++k) {
          ar += Hr[i][k] * Hr[j][k] + Hi[i][k] * Hi[j][k];
          ai += Hi[i][k] * Hr[j][k] - Hr[i][k] * Hi[j][k];
        }
        Lr[i][j] = ar; Li[i][j] = ai;
      }
    }
  #pragma unroll
  for (int i = 0; i < 4; ++i) Lr[i][i] += no;

  #pragma unroll
  for (int j = 0; j < 4; ++j) {
    double d = Lr[j][j];
    #pragma unroll
    for (int k = 0; k < j; ++k) d -= Lr[j][k] * Lr[j][k] + Li[j][k] * Li[j][k];
    d = sqrt(d);
    Lr[j][j] = d;
    double inv = 1.0 / d;
    #pragma unroll
    for (int i = j + 1; i < 4; ++i) {
      double cr = Lr[i][j], ci = Li[i][j];
      #pragma unroll
      for (int k = 0; k < j; ++k) {
        cr -= Lr[i][k] * Lr[j][k] + Li[i][k] * Li[j][k];
        ci -= Li[i][k] * Lr[j][k] - Lr[i][k] * Li[j][k];
      }
      Lr[i][j] = cr * inv; Li[i][j] = ci * inv;
    }
  }

  // forward solve: U = L^{-1} H (in place on H), v = L^{-1} y (in place on y)
  #pragma unroll
  for (int i = 0; i < 4; ++i) {
    double inv = 1.0 / Lr[i][i];
    #pragma unroll
    for (int j = 0; j < 4; ++j) {
      double ur = Hr[i][j], ui = Hi[i][j];
      #pragma unroll
      for (int k = 0; k < i; ++k) {
        ur -= Lr[i][k] * Hr[k][j] - Li[i][k] * Hi[k][j];
        ui -= Lr[i][k] * Hi[k][j] + Li[i][k] * Hr[k][j];
      }
      Hr[i][j] = ur * inv; Hi[i][j] = ui * inv;
    }
    double vr = yr[i], vi = yi[i];
    #pragma unroll
    for (int k = 0; k < i; ++k) {
      vr -= Lr[i][k] * yr[k] - Li[i][k] * yi[k];
      vi -= Lr[i][k] * yi[k] + Li[i][k] * yr[k];
    }
    yr[i] = vr * inv; yi[i] = vi * inv;
  }

  // per-UE: x_raw = U^H v, d_j = ||U[:,j]||^2, max-log LLRs
  #pragma unroll
  for (int j = 0; j < 4; ++j) {
    double dj = 0.0, rr = 0.0, ri = 0.0;
    #pragma unroll
    for (int i = 0; i < 4; ++i) {
      dj += Hr[i][j] * Hr[i][j] + Hi[i][j] * Hi[i][j];
      rr += Hr[i][j] * yr[i] + Hi[i][j] * yi[i];
      ri += Hr[i][j] * yi[i] - Hi[i][j] * yr[i];
    }
    double xh_r = rr / dj, xh_i = ri / dj;
    double noe = fmax(1.0 / dj - 1.0, 1e-12);

    double m0[4] = {-1e30, -1e30, -1e30, -1e30};
    double m1[4] = {-1e30, -1e30, -1e30, -1e30};
    #pragma unroll
    for (int p = 0; p < 16; ++p) {
      double pr, pi;
      qam_point(p, pr, pi);
      double dr = xh_r - pr, di = xh_i - pi;
      double met = -(dr * dr + di * di) / noe;
      #pragma unroll
      for (int k = 0; k < 4; ++k) {
        if ((p >> (3 - k)) & 1) m1[k] = fmax(m1[k], met);
        else                    m0[k] = fmax(m0[k], met);
      }
    }
    int cw = bt * 4 + j;
    #pragma unroll
    for (int k = 0; k < 4; ++k)
      Lch[(size_t)(s * 4 + k) * ncw + cw] = (float)(m0[k] - m1[k]);
  }
}

// ---------------- BP decoder (fp32 messages, hw-transcendental tanh/atanh) --
__device__ __forceinline__ float fast_tanh_half_clip(float m) {
  // tanh(clip(m*0.5, -9.9, 9.9)) with the reference's 1e-7 magnitude floor
  float x = fminf(fmaxf(m * 0.5f, -9.9f), 9.9f);
  float ax = fabsf(x);
  float e = __expf(2.0f * ax);           // e^{2|x|}, <= e^{19.8} ~ 4e8: safe
  float t = 1.0f - 2.0f / (e + 1.0f);    // tanh(|x|)
  t = copysignf(t, x);
  return (t >= 0.0f) ? fmaxf(t, 1e-7f) : fminf(t, -1e-7f);
}

__device__ __forceinline__ float two_atanh_clip(float r) {
  // 2*atanh(clip(r, -0.999999, 0.999999)) = log((1+r)/(1-r))
  r = fminf(fmaxf(r, -0.999999f), 0.999999f);
  return __logf((1.0f + r) / (1.0f - r));
}

__global__ void __launch_bounds__(256) k_vtot(const float* __restrict__ Lch, const float* __restrict__ c2v,
                                              const int* __restrict__ vdeg, const int* __restrict__ vlist,
                                              float* __restrict__ vtot, int ncw) {
  int cw = blockIdx.x * blockDim.x + threadIdx.x;
  int n = blockIdx.y;
  if (cw >= ncw) return;
  float acc = Lch[(size_t)n * ncw + cw];
  int d = vdeg[n];
  for (int k = 0; k < d; ++k)
    acc += c2v[(size_t)vlist[n * MAXVDEG + k] * ncw + cw];
  vtot[(size_t)n * ncw + cw] = acc;
}

__global__ void __launch_bounds__(256) k_check(const float* __restrict__ vtot, const int* __restrict__ vn,
                                               const int* __restrict__ cdeg, const int* __restrict__ clist,
                                               float* __restrict__ c2v, int ncw) {
  int cw = blockIdx.x * blockDim.x + threadIdx.x;
  int j = blockIdx.y;
  if (cw >= ncw) return;
  int d = cdeg[j];
  float tt[MAXCDEG];
  float prod = 1.0f;
  #pragma unroll
  for (int k = 0; k < MAXCDEG; ++k) {
    if (k < d) {
      int e = clist[j * MAXCDEG + k];
      float m = vtot[(size_t)vn[e] * ncw + cw] - c2v[(size_t)e * ncw + cw];
      float tv = fast_tanh_half_clip(m);
      tt[k] = tv;
      prod *= tv;
    }
  }
  #pragma unroll
  for (int k = 0; k < MAXCDEG; ++k) {
    if (k < d) {
      int e = clist[j * MAXCDEG + k];
      c2v[(size_t)e * ncw + cw] = two_atanh_clip(prod / tt[k]);
    }
  }
}

// iteration 0: c2v == 0 everywhere -> m_vc == Lch; writes every c2v entry.
__global__ void __launch_bounds__(256) k_check0(const float* __restrict__ Lch, const int* __restrict__ vn,
                                                const int* __restrict__ cdeg, const int* __restrict__ clist,
                                                float* __restrict__ c2v, int ncw) {
  int cw = blockIdx.x * blockDim.x + threadIdx.x;
  int j = blockIdx.y;
  if (cw >= ncw) return;
  int d = cdeg[j];
  float tt[MAXCDEG];
  float prod = 1.0f;
  #pragma unroll
  for (int k = 0; k < MAXCDEG; ++k) {
    if (k < d) {
      int e = clist[j * MAXCDEG + k];
      float tv = fast_tanh_half_clip(Lch[(size_t)vn[e] * ncw + cw]);
      tt[k] = tv;
      prod *= tv;
    }
  }
  #pragma unroll
  for (int k = 0; k < MAXCDEG; ++k) {
    if (k < d) {
      int e = clist[j * MAXCDEG + k];
      c2v[(size_t)e * ncw + cw] = two_atanh_clip(prod / tt[k]);
    }
  }
}

__global__ void __launch_bounds__(256) k_decide(const float* __restrict__ Lch, const float* __restrict__ c2v,
                                                const int* __restrict__ vdeg, const int* __restrict__ vlist,
                                                float* __restrict__ out, int ncw) {
  int cw = blockIdx.x * blockDim.x + threadIdx.x;
  int n = blockIdx.y;  // n < KK
  if (cw >= ncw) return;
  float acc = Lch[(size_t)n * ncw + cw];
  int d = vdeg[n];
  for (int k = 0; k < d; ++k)
    acc += c2v[(size_t)vlist[n * MAXVDEG + k] * ncw + cw];
  out[(size_t)ncw * KK + (size_t)cw * KK + n] = (acc < 0.0f) ? 1.0f : 0.0f;
}

// ---------------- launcher ----------------
extern "C" void kernel_launch(void* const* d_in, const int* in_sizes, int n_in,
                              void* d_out, int out_size, void* d_ws, size_t ws_size,
                              hipStream_t stream) {
  const float* ebno = (const float*)d_in[1];
  const int*   b    = (const int*)d_in[2];
  const int*   P    = (const int*)d_in[3];
  const int*   cn   = (const int*)d_in[4];
  const int*   vn   = (const int*)d_in[5];
  const float* h_re = (const float*)d_in[6];
  const float* h_im = (const float*)d_in[7];
  const float* nre  = (const float*)d_in[8];
  const float* nim  = (const float*)d_in[9];
  float* out = (float*)d_out;

  int E     = in_sizes[4];
  int batch = in_sizes[2] / (4 * KK);
  int ncw   = batch * 4;
  int T     = batch * NSYM;

  char* ws = (char*)d_ws;
  size_t off = 0;
  auto alloc = [&](size_t bytes) -> void* {
    void* p = ws + off;
    off += (bytes + 255) & ~(size_t)255;
    return p;
  };
  float*    Lch    = (float*)alloc((size_t)NNODES * ncw * 4);
  float*    c2v    = (float*)alloc((size_t)E * ncw * 4);
  float*    vtot   = (float*)alloc((size_t)NNODES * ncw * 4);
  int*      symidx = (int*)alloc((size_t)ncw * NSYM * 4);
  unsigned* Ppack  = (unsigned*)alloc((size_t)MM * 16 * 4);
  unsigned* bpack  = (unsigned*)alloc((size_t)ncw * 16 * 4);
  int*      cdeg   = (int*)alloc((size_t)MM * 4);
  int*      clist  = (int*)alloc((size_t)MM * MAXCDEG * 4);
  int*      vdeg   = (int*)alloc((size_t)NNODES * 4);
  int*      vlist  = (int*)alloc((size_t)NNODES * MAXVDEG * 4);
  (void)ws_size; (void)n_in; (void)out_size;

  const int tb = 256;
  hipMemsetAsync(cdeg, 0, (size_t)MM * 4, stream);
  hipMemsetAsync(vdeg, 0, (size_t)NNODES * 4, stream);

  k_pack_P<<<dim3((MM * 16 + tb - 1) / tb), dim3(tb), 0, stream>>>(P, Ppack);
  k_pack_b<<<dim3((ncw * 16 + tb - 1) / tb), dim3(tb), 0, stream>>>(b, bpack, ncw);
  k_sym<<<dim3((ncw * NSYM + tb - 1) / tb), dim3(tb), 0, stream>>>(bpack, Ppack, symidx, ncw);
  k_bf<<<dim3((ncw * KK + tb - 1) / tb), dim3(tb), 0, stream>>>(b, out, ncw * KK);
  k_fill<<<dim3((E + tb - 1) / tb), dim3(tb), 0, stream>>>(cn, vn, E, cdeg, clist, vdeg, vlist);
  k_lmmse<<<dim3((T + tb - 1) / tb), dim3(tb), 0, stream>>>(h_re, h_im, nre, nim, ebno, symidx, Lch, T, ncw);

  int cwb = (ncw + tb - 1) / tb;
  k_check0<<<dim3(cwb, MM), dim3(tb), 0, stream>>>(Lch, vn, cdeg, clist, c2v, ncw);
  for (int it = 1; it < NITERS; ++it) {
    k_vtot<<<dim3(cwb, NNODES), dim3(tb), 0, stream>>>(Lch, c2v, vdeg, vlist, vtot, ncw);
    k_check<<<dim3(cwb, MM), dim3(tb), 0, stream>>>(vtot, vn, cdeg, clist, c2v, ncw);
  }
  k_decide<<<dim3(cwb, KK), dim3(tb), 0, stream>>>(Lch, c2v, vdeg, vlist, out, ncw);
}

// Round 4
// 353.485 us; speedup vs baseline: 2.9144x; 1.0942x over previous
//
#include <hip/hip_runtime.h>
#include <math.h>

// Problem constants (from reference)
#define KK     500   // info bits
#define MM     500   // parity checks
#define NNODES 1000  // N = K + M variable nodes
#define NSYM   250   // N / BPS
#define NITERS 5
#define MAXVDEG 4    // info vars have degree exactly 3, parity vars 1
#define EMAX   2048  // E = 1500 + 500 = 2000 edges

// ---------------- bit packing ----------------
__global__ void __launch_bounds__(256) k_pack_P(const int* __restrict__ P, unsigned* __restrict__ Ppack) {
  int id = blockIdx.x * blockDim.x + threadIdx.x;
  if (id >= MM * 16) return;
  int j = id >> 4, w = id & 15;
  unsigned word = 0u;
  int base = w * 32;
  for (int bit = 0; bit < 32; ++bit) {
    int i = base + bit;
    if (i < KK && P[i * MM + j] != 0) word |= (1u << bit);
  }
  Ppack[j * 16 + w] = word;
}

__global__ void __launch_bounds__(256) k_pack_b(const int* __restrict__ b, unsigned* __restrict__ bpack, int ncw) {
  int id = blockIdx.x * blockDim.x + threadIdx.x;
  if (id >= ncw * 16) return;
  int cw = id >> 4, w = id & 15;
  unsigned word = 0u;
  int base = w * 32;
  for (int bit = 0; bit < 32; ++bit) {
    int i = base + bit;
    if (i < KK && b[cw * KK + i] != 0) word |= (1u << bit);
  }
  bpack[cw * 16 + w] = word;
}

// ---------------- symbol indices (encode + map) ----------------
__global__ void __launch_bounds__(256) k_sym(const unsigned* __restrict__ bpack, const unsigned* __restrict__ Ppack,
                                             int* __restrict__ symidx, int ncw) {
  int id = blockIdx.x * blockDim.x + threadIdx.x;
  if (id >= ncw * NSYM) return;
  int cw = id / NSYM, s = id - cw * NSYM;
  int idx = 0;
  #pragma unroll
  for (int k = 0; k < 4; ++k) {
    int n = 4 * s + k;
    int bit;
    if (n < KK) {
      bit = (bpack[cw * 16 + (n >> 5)] >> (n & 31)) & 1;
    } else {
      int j = n - KK;
      int cnt = 0;
      #pragma unroll
      for (int w = 0; w < 16; ++w) cnt += __popc(bpack[cw * 16 + w] & Ppack[j * 16 + w]);
      bit = cnt & 1;
    }
    idx = (idx << 1) | bit;  // MSB-first: weights 8,4,2,1
  }
  symidx[id] = idx;
}

// ---------------- output 0: bf = float(b) ----------------
__global__ void __launch_bounds__(256) k_bf(const int* __restrict__ b, float* __restrict__ out, int n) {
  int id = blockIdx.x * blockDim.x + threadIdx.x;
  if (id < n) out[id] = (float)b[id];
}

// ---------------- graph build: count -> scan -> fill (compact check-CSR) ----
__global__ void __launch_bounds__(256) k_count(const int* __restrict__ cn, int E, int* __restrict__ cdeg) {
  int e = blockIdx.x * blockDim.x + threadIdx.x;
  if (e < E) atomicAdd(&cdeg[cn[e]], 1);
}

// single block of 512 threads: exclusive prefix sum of cdeg into coff / cur
__global__ void __launch_bounds__(512) k_scan(const int* __restrict__ cdeg,
                                              int* __restrict__ coff, int* __restrict__ cur) {
  __shared__ int s[512];
  int tid = threadIdx.x;
  int v = (tid < MM) ? cdeg[tid] : 0;
  s[tid] = v;
  __syncthreads();
  for (int o = 1; o < 512; o <<= 1) {
    int x = (tid >= o) ? s[tid - o] : 0;
    __syncthreads();
    s[tid] += x;
    __syncthreads();
  }
  if (tid < MM) {
    int excl = s[tid] - v;
    coff[tid] = excl;
    cur[tid]  = excl;
    if (tid == MM - 1) coff[MM] = s[tid];
  }
}

// assign compact slot per edge; build var-node adjacency in SLOT ids
__global__ void __launch_bounds__(256) k_fill2(const int* __restrict__ cn, const int* __restrict__ vn, int E,
                                               int* __restrict__ cur, int* __restrict__ cvn,
                                               int* __restrict__ vdeg, int* __restrict__ vlist) {
  int e = blockIdx.x * blockDim.x + threadIdx.x;
  if (e >= E) return;
  int c = cn[e], n = vn[e];
  int slot = atomicAdd(&cur[c], 1);
  cvn[slot] = n;
  int t = atomicAdd(&vdeg[n], 1);
  if (t < MAXVDEG) vlist[n * MAXVDEG + t] = slot;
}

// ---------------- 16-QAM constellation point ----------------
__device__ __forceinline__ void qam_point(int p, double& re, double& im) {
  const double s = 0.31622776601683794;  // 1/sqrt(10)
  int b0 = (p >> 3) & 1, b1 = (p >> 2) & 1, b2 = (p >> 1) & 1, b3 = p & 1;
  re = (double)((1 - 2 * b0) * (2 - (1 - 2 * b2))) * s;
  im = (double)((1 - 2 * b1) * (2 - (1 - 2 * b3))) * s;
}

// ---------------- channel + LMMSE + max-log LLR (per symbol time t) --------
// fp64 math; output layout Lch2[bt][node][ue] so each thread stores a
// contiguous 64 B run (4x float4) -- round-3 profile showed the old
// node-major scatter cost ~100 MB of 32B-sector write inflation.
__global__ void __launch_bounds__(256, 1)
k_lmmse(const float* __restrict__ h_re, const float* __restrict__ h_im,
        const float* __restrict__ n_re, const float* __restrict__ n_im,
        const float* __restrict__ ebno, const int* __restrict__ symidx,
        float* __restrict__ Lch2, int T, int ncw) {
  int t = blockIdx.x * blockDim.x + threadIdx.x;
  if (t >= T) return;
  int bt = t / NSYM, s = t - bt * NSYM;

  double no = 1.0 / (pow(10.0, (double)ebno[0] * 0.1) * 2.0);  // BPS*RATE = 2
  const double is2 = 0.7071067811865475244;                     // 1/sqrt(2)

  double Hr[4][4], Hi[4][4];
  {
    const float4* hr4 = (const float4*)h_re;
    const float4* hi4 = (const float4*)h_im;
    #pragma unroll
    for (int i = 0; i < 4; ++i) {
      float4 a = hr4[t * 4 + i], c = hi4[t * 4 + i];
      Hr[i][0] = (double)a.x * is2; Hr[i][1] = (double)a.y * is2;
      Hr[i][2] = (double)a.z * is2; Hr[i][3] = (double)a.w * is2;
      Hi[i][0] = (double)c.x * is2; Hi[i][1] = (double)c.y * is2;
      Hi[i][2] = (double)c.z * is2; Hi[i][3] = (double)c.w * is2;
    }
  }

  double xr[4], xi[4];
  #pragma unroll
  for (int j = 0; j < 4; ++j) {
    int p = symidx[(bt * 4 + j) * NSYM + s];
    qam_point(p, xr[j], xi[j]);
  }

  // y = H x + w
  double sq = sqrt(no * 0.5);
  double yr[4], yi[4];
  {
    float4 wr = ((const float4*)n_re)[t];
    float4 wi = ((const float4*)n_im)[t];
    float wrv[4] = {wr.x, wr.y, wr.z, wr.w};
    float wiv[4] = {wi.x, wi.y, wi.z, wi.w};
    #pragma unroll
    for (int i = 0; i < 4; ++i) {
      double ar = (double)wrv[i] * sq;
      double ai = (double)wiv[i] * sq;
      #pragma unroll
      for (int j = 0; j < 4; ++j) {
        ar += Hr[i][j] * xr[j] - Hi[i][j] * xi[j];
        ai += Hr[i][j] * xi[j] + Hi[i][j] * xr[j];
      }
      yr[i] = ar; yi[i] = ai;
    }
  }

  // A = H H^H + no I, Cholesky A = L L^H
  double Lr[4][4], Li[4][4];
  #pragma unroll
  for (int i = 0; i < 4; ++i)
    #pragma unroll
    for (int j = 0; j < 4; ++j) { Lr[i][j] = 0.0; Li[i][j] = 0.0; }
  #pragma unroll
  for (int i = 0; i < 4; ++i)
    #pragma unroll
    for (int j = 0; j < 4; ++j) {
      if (j <= i) {
        double ar = 0.0, ai = 0.0;
        #pragma unroll
        for (int k = 0; k < 4; ++k) {
          ar += Hr[i][k] * Hr[j][k] + Hi[i][k] * Hi[j][k];
          ai += Hi[i][k] * Hr[j][k] - Hr[i][k] * Hi[j][k];
        }
        Lr[i][j] = ar; Li[i][j] = ai;
      }
    }
  #pragma unroll
  for (int i = 0; i < 4; ++i) Lr[i][i] += no;

  #pragma unroll
  for (int j = 0; j < 4; ++j) {
    double d = Lr[j][j];
    #pragma unroll
    for (int k = 0; k < j; ++k) d -= Lr[j][k] * Lr[j][k] + Li[j][k] * Li[j][k];
    d = sqrt(d);
    Lr[j][j] = d;
    double inv = 1.0 / d;
    #pragma unroll
    for (int i = j + 1; i < 4; ++i) {
      double cr = Lr[i][j], ci = Li[i][j];
      #pragma unroll
      for (int k = 0; k < j; ++k) {
        cr -= Lr[i][k] * Lr[j][k] + Li[i][k] * Li[j][k];
        ci -= Li[i][k] * Lr[j][k] - Lr[i][k] * Li[j][k];
      }
      Lr[i][j] = cr * inv; Li[i][j] = ci * inv;
    }
  }

  // forward solve: U = L^{-1} H (in place on H), v = L^{-1} y (in place on y)
  #pragma unroll
  for (int i = 0; i < 4; ++i) {
    double inv = 1.0 / Lr[i][i];
    #pragma unroll
    for (int j = 0; j < 4; ++j) {
      double ur = Hr[i][j], ui = Hi[i][j];
      #pragma unroll
      for (int k = 0; k < i; ++k) {
        ur -= Lr[i][k] * Hr[k][j] - Li[i][k] * Hi[k][j];
        ui -= Lr[i][k] * Hi[k][j] + Li[i][k] * Hr[k][j];
      }
      Hr[i][j] = ur * inv; Hi[i][j] = ui * inv;
    }
    double vr = yr[i], vi = yi[i];
    #pragma unroll
    for (int k = 0; k < i; ++k) {
      vr -= Lr[i][k] * yr[k] - Li[i][k] * yi[k];
      vi -= Lr[i][k] * yi[k] + Li[i][k] * yr[k];
    }
    yr[i] = vr * inv; yi[i] = vi * inv;
  }

  // per-UE LLRs into a 4x4 tile, then 4 contiguous float4 stores
  float llr[4][4];  // [bit k][ue j]
  #pragma unroll
  for (int j = 0; j < 4; ++j) {
    double dj = 0.0, rr = 0.0, ri = 0.0;
    #pragma unroll
    for (int i = 0; i < 4; ++i) {
      dj += Hr[i][j] * Hr[i][j] + Hi[i][j] * Hi[i][j];
      rr += Hr[i][j] * yr[i] + Hi[i][j] * yi[i];
      ri += Hr[i][j] * yi[i] - Hi[i][j] * yr[i];
    }
    double xh_r = rr / dj, xh_i = ri / dj;
    double noe = fmax(1.0 / dj - 1.0, 1e-12);

    double m0[4] = {-1e30, -1e30, -1e30, -1e30};
    double m1[4] = {-1e30, -1e30, -1e30, -1e30};
    #pragma unroll
    for (int p = 0; p < 16; ++p) {
      double pr, pi;
      qam_point(p, pr, pi);
      double dr = xh_r - pr, di = xh_i - pi;
      double met = -(dr * dr + di * di) / noe;
      #pragma unroll
      for (int k = 0; k < 4; ++k) {
        if ((p >> (3 - k)) & 1) m1[k] = fmax(m1[k], met);
        else                    m0[k] = fmax(m0[k], met);
      }
    }
    #pragma unroll
    for (int k = 0; k < 4; ++k) llr[k][j] = (float)(m0[k] - m1[k]);
  }
  float4* dst = (float4*)(Lch2 + (size_t)bt * NNODES * 4) + 4 * s;
  #pragma unroll
  for (int k = 0; k < 4; ++k)
    dst[k] = make_float4(llr[k][0], llr[k][1], llr[k][2], llr[k][3]);
}

// ---------------- fused LDS-resident BP decoder ----------------
__device__ __forceinline__ float fast_tanh_half_clip(float m) {
  // tanh(clip(m*0.5, -9.9, 9.9)) with the reference's 1e-7 magnitude floor
  float x = fminf(fmaxf(m * 0.5f, -9.9f), 9.9f);
  float ax = fabsf(x);
  float e = __expf(2.0f * ax);
  float t = 1.0f - 2.0f / (e + 1.0f);
  t = copysignf(t, x);
  return (t >= 0.0f) ? fmaxf(t, 1e-7f) : fminf(t, -1e-7f);
}

__device__ __forceinline__ float two_atanh_clip(float r) {
  r = fminf(fmaxf(r, -0.999999f), 0.999999f);
  return __logf((1.0f + r) / (1.0f - r));
}

// one block per codeword; all messages live in LDS (~34.5 KB/block)
__global__ void __launch_bounds__(256) k_bp(const float* __restrict__ Lch2,
                                            const int* __restrict__ vdeg, const int* __restrict__ vlist,
                                            const int* __restrict__ coff, const int* __restrict__ cvn,
                                            float* __restrict__ out, int E, int ncw) {
  __shared__ float sL[NNODES];    // channel LLRs
  __shared__ float sV[NNODES];    // vtot
  __shared__ float sC[EMAX];      // c2v messages (slot-indexed)
  __shared__ float sT[EMAX];      // tanh(v2c/2) per edge
  __shared__ int   sCv[EMAX];     // var node per slot
  __shared__ int   sOff[MM + 1];  // check CSR offsets

  int tid = threadIdx.x;
  int cw = blockIdx.x;
  int bt = cw >> 2, jj = cw & 3;

  const float* src = Lch2 + (size_t)bt * NNODES * 4 + jj;
  for (int n = tid; n < NNODES; n += 256) sL[n] = src[(size_t)n * 4];
  for (int e = tid; e < E; e += 256) { sC[e] = 0.0f; sCv[e] = cvn[e]; }
  for (int c = tid; c <= MM; c += 256) sOff[c] = coff[c];

  // per-thread var-node structure (info deg==3, parity deg==1)
  int vd[4]; int vl[4][4];
  #pragma unroll
  for (int i = 0; i < 4; ++i) {
    int n = tid + 256 * i;
    vd[i] = 0;
    if (n < NNODES) {
      vd[i] = vdeg[n];
      #pragma unroll
      for (int k = 0; k < 4; ++k) vl[i][k] = vlist[n * MAXVDEG + k];
    }
  }
  __syncthreads();

  for (int it = 0; it < NITERS; ++it) {
    // vtot (node-parallel)
    #pragma unroll
    for (int i = 0; i < 4; ++i) {
      int n = tid + 256 * i;
      if (n < NNODES) {
        float acc = sL[n];
        int d = vd[i];
        #pragma unroll
        for (int k = 0; k < MAXVDEG; ++k)
          if (k < d) acc += sC[vl[i][k]];
        sV[n] = acc;
      }
    }
    __syncthreads();
    // tanh of v2c messages (edge-parallel, no divergence)
    for (int e = tid; e < E; e += 256)
      sT[e] = fast_tanh_half_clip(sV[sCv[e]] - sC[e]);
    __syncthreads();
    // check update (check-parallel over compact CSR ranges)
    for (int c = tid; c < MM; c += 256) {
      int beg = sOff[c], end = sOff[c + 1];
      float prod = 1.0f;
      for (int e = beg; e < end; ++e) prod *= sT[e];
      for (int e = beg; e < end; ++e)
        sC[e] = two_atanh_clip(prod / sT[e]);
    }
    __syncthreads();
  }

  // decide info bits
  float* o = out + (size_t)ncw * KK + (size_t)cw * KK;
  #pragma unroll
  for (int i = 0; i < 2; ++i) {
    int n = tid + 256 * i;
    if (n < KK) {
      float acc = sL[n];
      int d = vd[i];
      #pragma unroll
      for (int k = 0; k < MAXVDEG; ++k)
        if (k < d) acc += sC[vl[i][k]];
      o[n] = (acc < 0.0f) ? 1.0f : 0.0f;
    }
  }
}

// ---------------- launcher ----------------
extern "C" void kernel_launch(void* const* d_in, const int* in_sizes, int n_in,
                              void* d_out, int out_size, void* d_ws, size_t ws_size,
                              hipStream_t stream) {
  const float* ebno = (const float*)d_in[1];
  const int*   b    = (const int*)d_in[2];
  const int*   P    = (const int*)d_in[3];
  const int*   cn   = (const int*)d_in[4];
  const int*   vn   = (const int*)d_in[5];
  const float* h_re = (const float*)d_in[6];
  const float* h_im = (const float*)d_in[7];
  const float* nre  = (const float*)d_in[8];
  const float* nim  = (const float*)d_in[9];
  float* out = (float*)d_out;

  int E     = in_sizes[4];
  int batch = in_sizes[2] / (4 * KK);
  int ncw   = batch * 4;
  int T     = batch * NSYM;

  char* ws = (char*)d_ws;
  size_t off = 0;
  auto alloc = [&](size_t bytes) -> void* {
    void* p = ws + off;
    off += (bytes + 255) & ~(size_t)255;
    return p;
  };
  float*    Lch2   = (float*)alloc((size_t)NNODES * ncw * 4);
  int*      symidx = (int*)alloc((size_t)ncw * NSYM * 4);
  unsigned* Ppack  = (unsigned*)alloc((size_t)MM * 16 * 4);
  unsigned* bpack  = (unsigned*)alloc((size_t)ncw * 16 * 4);
  int*      cdeg   = (int*)alloc((size_t)MM * 4);
  int*      coff   = (int*)alloc((size_t)(MM + 1) * 4);
  int*      cur    = (int*)alloc((size_t)MM * 4);
  int*      cvn    = (int*)alloc((size_t)EMAX * 4);
  int*      vdeg   = (int*)alloc((size_t)NNODES * 4);
  int*      vlist  = (int*)alloc((size_t)NNODES * MAXVDEG * 4);
  (void)ws_size; (void)n_in; (void)out_size;

  const int tb = 256;
  hipMemsetAsync(cdeg, 0, (size_t)MM * 4, stream);
  hipMemsetAsync(vdeg, 0, (size_t)NNODES * 4, stream);

  k_pack_P<<<dim3((MM * 16 + tb - 1) / tb), dim3(tb), 0, stream>>>(P, Ppack);
  k_pack_b<<<dim3((ncw * 16 + tb - 1) / tb), dim3(tb), 0, stream>>>(b, bpack, ncw);
  k_sym<<<dim3((ncw * NSYM + tb - 1) / tb), dim3(tb), 0, stream>>>(bpack, Ppack, symidx, ncw);
  k_bf<<<dim3((ncw * KK + tb - 1) / tb), dim3(tb), 0, stream>>>(b, out, ncw * KK);

  k_count<<<dim3((E + tb - 1) / tb), dim3(tb), 0, stream>>>(cn, E, cdeg);
  k_scan<<<dim3(1), dim3(512), 0, stream>>>(cdeg, coff, cur);
  k_fill2<<<dim3((E + tb - 1) / tb), dim3(tb), 0, stream>>>(cn, vn, E, cur, cvn, vdeg, vlist);

  k_lmmse<<<dim3((T + tb - 1) / tb), dim3(tb), 0, stream>>>(h_re, h_im, nre, nim, ebno, symidx, Lch2, T, ncw);

  k_bp<<<dim3(ncw), dim3(tb), 0, stream>>>(Lch2, vdeg, vlist, coff, cvn, out, E, ncw);
}

// Round 5
// 292.818 us; speedup vs baseline: 3.5183x; 1.2072x over previous
//
#include <hip/hip_runtime.h>
#include <math.h>

// Problem constants (from reference)
#define KK     500   // info bits
#define MM     500   // parity checks
#define NNODES 1000  // N = K + M variable nodes
#define NSYM   250   // N / BPS
#define NITERS 5
#define MAXVDEG 4    // info vars have degree exactly 3, parity vars 1
#define EMAX   2048  // E = 1500 + 500 = 2000 edges

// ---------------- bit packing ----------------
__global__ void __launch_bounds__(256) k_pack_P(const int* __restrict__ P, unsigned* __restrict__ Ppack) {
  int id = blockIdx.x * blockDim.x + threadIdx.x;
  if (id >= MM * 16) return;
  int j = id >> 4, w = id & 15;
  unsigned word = 0u;
  int base = w * 32;
  for (int bit = 0; bit < 32; ++bit) {
    int i = base + bit;
    if (i < KK && P[i * MM + j] != 0) word |= (1u << bit);
  }
  Ppack[j * 16 + w] = word;
}

__global__ void __launch_bounds__(256) k_pack_b(const int* __restrict__ b, unsigned* __restrict__ bpack, int ncw) {
  int id = blockIdx.x * blockDim.x + threadIdx.x;
  if (id >= ncw * 16) return;
  int cw = id >> 4, w = id & 15;
  unsigned word = 0u;
  int base = w * 32;
  for (int bit = 0; bit < 32; ++bit) {
    int i = base + bit;
    if (i < KK && b[cw * KK + i] != 0) word |= (1u << bit);
  }
  bpack[cw * 16 + w] = word;
}

// ---------------- symbol indices (encode + map) ----------------
__global__ void __launch_bounds__(256) k_sym(const unsigned* __restrict__ bpack, const unsigned* __restrict__ Ppack,
                                             int* __restrict__ symidx, int ncw) {
  int id = blockIdx.x * blockDim.x + threadIdx.x;
  if (id >= ncw * NSYM) return;
  int cw = id / NSYM, s = id - cw * NSYM;
  int idx = 0;
  #pragma unroll
  for (int k = 0; k < 4; ++k) {
    int n = 4 * s + k;
    int bit;
    if (n < KK) {
      bit = (bpack[cw * 16 + (n >> 5)] >> (n & 31)) & 1;
    } else {
      int j = n - KK;
      int cnt = 0;
      #pragma unroll
      for (int w = 0; w < 16; ++w) cnt += __popc(bpack[cw * 16 + w] & Ppack[j * 16 + w]);
      bit = cnt & 1;
    }
    idx = (idx << 1) | bit;  // MSB-first: weights 8,4,2,1
  }
  symidx[id] = idx;
}

// ---------------- output 0: bf = float(b) ----------------
__global__ void __launch_bounds__(256) k_bf(const int* __restrict__ b, float* __restrict__ out, int n) {
  int id = blockIdx.x * blockDim.x + threadIdx.x;
  if (id < n) out[id] = (float)b[id];
}

// ---------------- graph build: count -> scan -> fill (compact check-CSR) ----
__global__ void __launch_bounds__(256) k_count(const int* __restrict__ cn, int E, int* __restrict__ cdeg) {
  int e = blockIdx.x * blockDim.x + threadIdx.x;
  if (e < E) atomicAdd(&cdeg[cn[e]], 1);
}

// single block of 512 threads: exclusive prefix sum of cdeg into coff / cur
__global__ void __launch_bounds__(512) k_scan(const int* __restrict__ cdeg,
                                              int* __restrict__ coff, int* __restrict__ cur) {
  __shared__ int s[512];
  int tid = threadIdx.x;
  int v = (tid < MM) ? cdeg[tid] : 0;
  s[tid] = v;
  __syncthreads();
  for (int o = 1; o < 512; o <<= 1) {
    int x = (tid >= o) ? s[tid - o] : 0;
    __syncthreads();
    s[tid] += x;
    __syncthreads();
  }
  if (tid < MM) {
    int excl = s[tid] - v;
    coff[tid] = excl;
    cur[tid]  = excl;
    if (tid == MM - 1) coff[MM] = s[tid];
  }
}

// assign compact slot per edge; cinfo[slot] = (check << 16) | varnode;
// var-node adjacency in SLOT ids
__global__ void __launch_bounds__(256) k_fill2(const int* __restrict__ cn, const int* __restrict__ vn, int E,
                                               int* __restrict__ cur, int* __restrict__ cinfo,
                                               int* __restrict__ vdeg, int* __restrict__ vlist) {
  int e = blockIdx.x * blockDim.x + threadIdx.x;
  if (e >= E) return;
  int c = cn[e], n = vn[e];
  int slot = atomicAdd(&cur[c], 1);
  cinfo[slot] = (c << 16) | n;
  int t = atomicAdd(&vdeg[n], 1);
  if (t < MAXVDEG) vlist[n * MAXVDEG + t] = slot;
}

// ---------------- 16-QAM constellation point ----------------
__device__ __forceinline__ void qam_point(int p, double& re, double& im) {
  const double s = 0.31622776601683794;  // 1/sqrt(10)
  int b0 = (p >> 3) & 1, b1 = (p >> 2) & 1, b2 = (p >> 1) & 1, b3 = p & 1;
  re = (double)((1 - 2 * b0) * (2 - (1 - 2 * b2))) * s;
  im = (double)((1 - 2 * b1) * (2 - (1 - 2 * b3))) * s;
}

// ---------------- channel + LMMSE + max-log LLR (per symbol time t) --------
// fp64 math; Lch2[bt][node][ue] layout: each thread stores 4 contiguous float4
__global__ void __launch_bounds__(256, 1)
k_lmmse(const float* __restrict__ h_re, const float* __restrict__ h_im,
        const float* __restrict__ n_re, const float* __restrict__ n_im,
        const float* __restrict__ ebno, const int* __restrict__ symidx,
        float* __restrict__ Lch2, int T, int ncw) {
  int t = blockIdx.x * blockDim.x + threadIdx.x;
  if (t >= T) return;
  int bt = t / NSYM, s = t - bt * NSYM;

  double no = 1.0 / (pow(10.0, (double)ebno[0] * 0.1) * 2.0);  // BPS*RATE = 2
  const double is2 = 0.7071067811865475244;                     // 1/sqrt(2)

  double Hr[4][4], Hi[4][4];
  {
    const float4* hr4 = (const float4*)h_re;
    const float4* hi4 = (const float4*)h_im;
    #pragma unroll
    for (int i = 0; i < 4; ++i) {
      float4 a = hr4[t * 4 + i], c = hi4[t * 4 + i];
      Hr[i][0] = (double)a.x * is2; Hr[i][1] = (double)a.y * is2;
      Hr[i][2] = (double)a.z * is2; Hr[i][3] = (double)a.w * is2;
      Hi[i][0] = (double)c.x * is2; Hi[i][1] = (double)c.y * is2;
      Hi[i][2] = (double)c.z * is2; Hi[i][3] = (double)c.w * is2;
    }
  }

  double xr[4], xi[4];
  #pragma unroll
  for (int j = 0; j < 4; ++j) {
    int p = symidx[(bt * 4 + j) * NSYM + s];
    qam_point(p, xr[j], xi[j]);
  }

  // y = H x + w
  double sq = sqrt(no * 0.5);
  double yr[4], yi[4];
  {
    float4 wr = ((const float4*)n_re)[t];
    float4 wi = ((const float4*)n_im)[t];
    float wrv[4] = {wr.x, wr.y, wr.z, wr.w};
    float wiv[4] = {wi.x, wi.y, wi.z, wi.w};
    #pragma unroll
    for (int i = 0; i < 4; ++i) {
      double ar = (double)wrv[i] * sq;
      double ai = (double)wiv[i] * sq;
      #pragma unroll
      for (int j = 0; j < 4; ++j) {
        ar += Hr[i][j] * xr[j] - Hi[i][j] * xi[j];
        ai += Hr[i][j] * xi[j] + Hi[i][j] * xr[j];
      }
      yr[i] = ar; yi[i] = ai;
    }
  }

  // A = H H^H + no I, Cholesky A = L L^H
  double Lr[4][4], Li[4][4];
  #pragma unroll
  for (int i = 0; i < 4; ++i)
    #pragma unroll
    for (int j = 0; j < 4; ++j) { Lr[i][j] = 0.0; Li[i][j] = 0.0; }
  #pragma unroll
  for (int i = 0; i < 4; ++i)
    #pragma unroll
    for (int j = 0; j < 4; ++j) {
      if (j <= i) {
        double ar = 0.0, ai = 0.0;
        #pragma unroll
        for (int k = 0; k < 4; ++k) {
          ar += Hr[i][k] * Hr[j][k] + Hi[i][k] * Hi[j][k];
          ai += Hi[i][k] * Hr[j][k] - Hr[i][k] * Hi[j][k];
        }
        Lr[i][j] = ar; Li[i][j] = ai;
      }
    }
  #pragma unroll
  for (int i = 0; i < 4; ++i) Lr[i][i] += no;

  #pragma unroll
  for (int j = 0; j < 4; ++j) {
    double d = Lr[j][j];
    #pragma unroll
    for (int k = 0; k < j; ++k) d -= Lr[j][k] * Lr[j][k] + Li[j][k] * Li[j][k];
    d = sqrt(d);
    Lr[j][j] = d;
    double inv = 1.0 / d;
    #pragma unroll
    for (int i = j + 1; i < 4; ++i) {
      double cr = Lr[i][j], ci = Li[i][j];
      #pragma unroll
      for (int k = 0; k < j; ++k) {
        cr -= Lr[i][k] * Lr[j][k] + Li[i][k] * Li[j][k];
        ci -= Li[i][k] * Lr[j][k] - Lr[i][k] * Li[j][k];
      }
      Lr[i][j] = cr * inv; Li[i][j] = ci * inv;
    }
  }

  // forward solve: U = L^{-1} H (in place on H), v = L^{-1} y (in place on y)
  #pragma unroll
  for (int i = 0; i < 4; ++i) {
    double inv = 1.0 / Lr[i][i];
    #pragma unroll
    for (int j = 0; j < 4; ++j) {
      double ur = Hr[i][j], ui = Hi[i][j];
      #pragma unroll
      for (int k = 0; k < i; ++k) {
        ur -= Lr[i][k] * Hr[k][j] - Li[i][k] * Hi[k][j];
        ui -= Lr[i][k] * Hi[k][j] + Li[i][k] * Hr[k][j];
      }
      Hr[i][j] = ur * inv; Hi[i][j] = ui * inv;
    }
    double vr = yr[i], vi = yi[i];
    #pragma unroll
    for (int k = 0; k < i; ++k) {
      vr -= Lr[i][k] * yr[k] - Li[i][k] * yi[k];
      vi -= Lr[i][k] * yi[k] + Li[i][k] * yr[k];
    }
    yr[i] = vr * inv; yi[i] = vi * inv;
  }

  // per-UE LLRs into a 4x4 tile, then 4 contiguous float4 stores
  float llr[4][4];  // [bit k][ue j]
  #pragma unroll
  for (int j = 0; j < 4; ++j) {
    double dj = 0.0, rr = 0.0, ri = 0.0;
    #pragma unroll
    for (int i = 0; i < 4; ++i) {
      dj += Hr[i][j] * Hr[i][j] + Hi[i][j] * Hi[i][j];
      rr += Hr[i][j] * yr[i] + Hi[i][j] * yi[i];
      ri += Hr[i][j] * yi[i] - Hi[i][j] * yr[i];
    }
    double xh_r = rr / dj, xh_i = ri / dj;
    double noe = fmax(1.0 / dj - 1.0, 1e-12);

    double m0[4] = {-1e30, -1e30, -1e30, -1e30};
    double m1[4] = {-1e30, -1e30, -1e30, -1e30};
    #pragma unroll
    for (int p = 0; p < 16; ++p) {
      double pr, pi;
      qam_point(p, pr, pi);
      double dr = xh_r - pr, di = xh_i - pi;
      double met = -(dr * dr + di * di) / noe;
      #pragma unroll
      for (int k = 0; k < 4; ++k) {
        if ((p >> (3 - k)) & 1) m1[k] = fmax(m1[k], met);
        else                    m0[k] = fmax(m0[k], met);
      }
    }
    #pragma unroll
    for (int k = 0; k < 4; ++k) llr[k][j] = (float)(m0[k] - m1[k]);
  }
  float4* dst = (float4*)(Lch2 + (size_t)bt * NNODES * 4) + 4 * s;
  #pragma unroll
  for (int k = 0; k < 4; ++k)
    dst[k] = make_float4(llr[k][0], llr[k][1], llr[k][2], llr[k][3]);
}

// ---------------- fused LDS-resident BP decoder ----------------
// All divisions via __fdividef (rcp+mul); exp/log native hw ops.
__device__ __forceinline__ float fast_tanh_half_clip(float m) {
  // tanh(clip(m*0.5, -9.9, 9.9)) with the reference's 1e-7 magnitude floor
  float x = fminf(fmaxf(m * 0.5f, -9.9f), 9.9f);
  float ax = fabsf(x);
  float e = __expf(2.0f * ax);
  float t = 1.0f - __fdividef(2.0f, e + 1.0f);
  t = copysignf(t, x);
  return (t >= 0.0f) ? fmaxf(t, 1e-7f) : fminf(t, -1e-7f);
}

// one block per codeword; messages in LDS (~36 KB/block -> 4 blocks/CU).
// Per iteration: node-parallel vtot, edge-parallel tanh, check-parallel
// product (multiplies only under divergence), edge-parallel atanh
// (all transcendentals in uniform control flow).
__global__ void __launch_bounds__(256) k_bp(const float* __restrict__ Lch2,
                                            const int* __restrict__ vdeg, const int* __restrict__ vlist,
                                            const int* __restrict__ coff, const int* __restrict__ cinfo,
                                            float* __restrict__ out, int E, int ncw) {
  __shared__ float sL[NNODES];    // channel LLRs
  __shared__ float sV[NNODES];    // vtot
  __shared__ float sC[EMAX];      // c2v messages (slot-indexed)
  __shared__ float sT[EMAX];      // tanh(v2c/2) per edge
  __shared__ float sP[MM];        // per-check product
  __shared__ int   sInfo[EMAX];   // (check << 16) | varnode per slot
  __shared__ int   sOff[MM + 1];  // check CSR offsets

  int tid = threadIdx.x;
  int cw = blockIdx.x;
  int bt = cw >> 2, jj = cw & 3;

  const float* src = Lch2 + (size_t)bt * NNODES * 4 + jj;
  for (int n = tid; n < NNODES; n += 256) sL[n] = src[(size_t)n * 4];
  for (int e = tid; e < E; e += 256) sInfo[e] = cinfo[e];
  for (int c = tid; c <= MM; c += 256) sOff[c] = coff[c];

  // per-thread var-node structure (info deg==3, parity deg==1)
  int vd[4]; int vl[4][4];
  #pragma unroll
  for (int i = 0; i < 4; ++i) {
    int n = tid + 256 * i;
    vd[i] = 0;
    if (n < NNODES) {
      vd[i] = vdeg[n];
      #pragma unroll
      for (int k = 0; k < 4; ++k) vl[i][k] = vlist[n * MAXVDEG + k];
    }
  }
  __syncthreads();

  for (int it = 0; it < NITERS; ++it) {
    if (it == 0) {
      // c2v == 0: v2c message is just the channel LLR
      for (int e = tid; e < E; e += 256)
        sT[e] = fast_tanh_half_clip(sL[sInfo[e] & 0xffff]);
    } else {
      // vtot (node-parallel)
      #pragma unroll
      for (int i = 0; i < 4; ++i) {
        int n = tid + 256 * i;
        if (n < NNODES) {
          float acc = sL[n];
          int d = vd[i];
          #pragma unroll
          for (int k = 0; k < MAXVDEG; ++k)
            if (k < d) acc += sC[vl[i][k]];
          sV[n] = acc;
        }
      }
      __syncthreads();
      // tanh of v2c messages (edge-parallel, uniform)
      for (int e = tid; e < E; e += 256)
        sT[e] = fast_tanh_half_clip(sV[sInfo[e] & 0xffff] - sC[e]);
    }
    __syncthreads();
    // per-check product (check-parallel; multiplies only)
    for (int c = tid; c < MM; c += 256) {
      int beg = sOff[c], end = sOff[c + 1];
      float p = 1.0f;
      for (int e = beg; e < end; ++e) p *= sT[e];
      sP[c] = p;
    }
    __syncthreads();
    // c2v update (edge-parallel, uniform; all transcendentals here)
    for (int e = tid; e < E; e += 256) {
      float r = __fdividef(sP[sInfo[e] >> 16], sT[e]);
      r = fminf(fmaxf(r, -0.999999f), 0.999999f);
      sC[e] = __logf(__fdividef(1.0f + r, 1.0f - r));
    }
    __syncthreads();
  }

  // decide info bits
  float* o = out + (size_t)ncw * KK + (size_t)cw * KK;
  #pragma unroll
  for (int i = 0; i < 2; ++i) {
    int n = tid + 256 * i;
    if (n < KK) {
      float acc = sL[n];
      int d = vd[i];
      #pragma unroll
      for (int k = 0; k < MAXVDEG; ++k)
        if (k < d) acc += sC[vl[i][k]];
      o[n] = (acc < 0.0f) ? 1.0f : 0.0f;
    }
  }
}

// ---------------- launcher ----------------
extern "C" void kernel_launch(void* const* d_in, const int* in_sizes, int n_in,
                              void* d_out, int out_size, void* d_ws, size_t ws_size,
                              hipStream_t stream) {
  const float* ebno = (const float*)d_in[1];
  const int*   b    = (const int*)d_in[2];
  const int*   P    = (const int*)d_in[3];
  const int*   cn   = (const int*)d_in[4];
  const int*   vn   = (const int*)d_in[5];
  const float* h_re = (const float*)d_in[6];
  const float* h_im = (const float*)d_in[7];
  const float* nre  = (const float*)d_in[8];
  const float* nim  = (const float*)d_in[9];
  float* out = (float*)d_out;

  int E     = in_sizes[4];
  int batch = in_sizes[2] / (4 * KK);
  int ncw   = batch * 4;
  int T     = batch * NSYM;

  char* ws = (char*)d_ws;
  size_t off = 0;
  auto alloc = [&](size_t bytes) -> void* {
    void* p = ws + off;
    off += (bytes + 255) & ~(size_t)255;
    return p;
  };
  float*    Lch2   = (float*)alloc((size_t)NNODES * ncw * 4);
  int*      symidx = (int*)alloc((size_t)ncw * NSYM * 4);
  unsigned* Ppack  = (unsigned*)alloc((size_t)MM * 16 * 4);
  unsigned* bpack  = (unsigned*)alloc((size_t)ncw * 16 * 4);
  int*      cdeg   = (int*)alloc((size_t)MM * 4);
  int*      coff   = (int*)alloc((size_t)(MM + 1) * 4);
  int*      cur    = (int*)alloc((size_t)MM * 4);
  int*      cinfo  = (int*)alloc((size_t)EMAX * 4);
  int*      vdeg   = (int*)alloc((size_t)NNODES * 4);
  int*      vlist  = (int*)alloc((size_t)NNODES * MAXVDEG * 4);
  (void)ws_size; (void)n_in; (void)out_size;

  const int tb = 256;
  hipMemsetAsync(cdeg, 0, (size_t)MM * 4, stream);
  hipMemsetAsync(vdeg, 0, (size_t)NNODES * 4, stream);

  k_pack_P<<<dim3((MM * 16 + tb - 1) / tb), dim3(tb), 0, stream>>>(P, Ppack);
  k_pack_b<<<dim3((ncw * 16 + tb - 1) / tb), dim3(tb), 0, stream>>>(b, bpack, ncw);
  k_sym<<<dim3((ncw * NSYM + tb - 1) / tb), dim3(tb), 0, stream>>>(bpack, Ppack, symidx, ncw);
  k_bf<<<dim3((ncw * KK + tb - 1) / tb), dim3(tb), 0, stream>>>(b, out, ncw * KK);

  k_count<<<dim3((E + tb - 1) / tb), dim3(tb), 0, stream>>>(cn, E, cdeg);
  k_scan<<<dim3(1), dim3(512), 0, stream>>>(cdeg, coff, cur);
  k_fill2<<<dim3((E + tb - 1) / tb), dim3(tb), 0, stream>>>(cn, vn, E, cur, cinfo, vdeg, vlist);

  k_lmmse<<<dim3((T + tb - 1) / tb), dim3(tb), 0, stream>>>(h_re, h_im, nre, nim, ebno, symidx, Lch2, T, ncw);

  k_bp<<<dim3(ncw), dim3(tb), 0, stream>>>(Lch2, vdeg, vlist, coff, cinfo, out, E, ncw);
}

// Round 6
// 266.006 us; speedup vs baseline: 3.8729x; 1.1008x over previous
//
#include <hip/hip_runtime.h>
#include <math.h>

// Problem constants (from reference)
#define KK     500   // info bits
#define MM     500   // parity checks
#define NNODES 1000  // N = K + M variable nodes
#define NSYM   250   // N / BPS
#define NITERS 5
#define MAXVDEG 4    // info vars degree exactly 3, parity vars 1 (row weight of P is 3)
#define EMAX   2048  // E = 2000 edges
#define TB     256

// ---------------- bit packing ----------------
__global__ void __launch_bounds__(256) k_pack_P(const int* __restrict__ P, unsigned* __restrict__ Ppack) {
  int id = blockIdx.x * blockDim.x + threadIdx.x;
  if (id >= MM * 16) return;
  int j = id >> 4, w = id & 15;
  unsigned word = 0u;
  int base = w * 32;
  for (int bit = 0; bit < 32; ++bit) {
    int i = base + bit;
    if (i < KK && P[i * MM + j] != 0) word |= (1u << bit);
  }
  Ppack[j * 16 + w] = word;
}

__global__ void __launch_bounds__(256) k_pack_b(const int* __restrict__ b, unsigned* __restrict__ bpack, int ncw) {
  int id = blockIdx.x * blockDim.x + threadIdx.x;
  if (id >= ncw * 16) return;
  int cw = id >> 4, w = id & 15;
  unsigned word = 0u;
  int base = w * 32;
  for (int bit = 0; bit < 32; ++bit) {
    int i = base + bit;
    if (i < KK && b[cw * KK + i] != 0) word |= (1u << bit);
  }
  bpack[cw * 16 + w] = word;
}

// ---------------- symbol indices, layout [bt][s][ue] ----------------
__global__ void __launch_bounds__(256) k_sym(const unsigned* __restrict__ bpack, const unsigned* __restrict__ Ppack,
                                             int* __restrict__ symidx2, int ncw) {
  int id = blockIdx.x * blockDim.x + threadIdx.x;
  if (id >= ncw * NSYM) return;
  int cw = id / NSYM, s = id - cw * NSYM;
  int idx = 0;
  #pragma unroll
  for (int k = 0; k < 4; ++k) {
    int n = 4 * s + k;
    int bit;
    if (n < KK) {
      bit = (bpack[cw * 16 + (n >> 5)] >> (n & 31)) & 1;
    } else {
      int j = n - KK;
      int cnt = 0;
      #pragma unroll
      for (int w = 0; w < 16; ++w) cnt += __popc(bpack[cw * 16 + w] & Ppack[j * 16 + w]);
      bit = cnt & 1;
    }
    idx = (idx << 1) | bit;  // MSB-first: weights 8,4,2,1
  }
  symidx2[(((cw >> 2) * NSYM) + s) * 4 + (cw & 3)] = idx;
}

// ---------------- output 0: bf = float(b) ----------------
__global__ void __launch_bounds__(256) k_bf(const int* __restrict__ b, float* __restrict__ out, int n) {
  int id = blockIdx.x * blockDim.x + threadIdx.x;
  if (id < n) out[id] = (float)b[id];
}

// ---------------- graph build: count -> scan -> fill (compact check-CSR) ----
__global__ void __launch_bounds__(256) k_count(const int* __restrict__ cn, int E, int* __restrict__ cdeg) {
  int e = blockIdx.x * blockDim.x + threadIdx.x;
  if (e < E) atomicAdd(&cdeg[cn[e]], 1);
}

__global__ void __launch_bounds__(512) k_scan(const int* __restrict__ cdeg,
                                              int* __restrict__ coff, int* __restrict__ cur) {
  __shared__ int s[512];
  int tid = threadIdx.x;
  int v = (tid < MM) ? cdeg[tid] : 0;
  s[tid] = v;
  __syncthreads();
  for (int o = 1; o < 512; o <<= 1) {
    int x = (tid >= o) ? s[tid - o] : 0;
    __syncthreads();
    s[tid] += x;
    __syncthreads();
  }
  if (tid < MM) {
    int excl = s[tid] - v;
    coff[tid] = excl;
    cur[tid]  = excl;
    if (tid == MM - 1) coff[MM] = s[tid];
  }
}

__global__ void __launch_bounds__(256) k_fill2(const int* __restrict__ cn, const int* __restrict__ vn, int E,
                                               int* __restrict__ cur, int* __restrict__ cinfo,
                                               int* __restrict__ vdeg, int* __restrict__ vlist) {
  int e = blockIdx.x * blockDim.x + threadIdx.x;
  if (e >= E) return;
  int c = cn[e], n = vn[e];
  int slot = atomicAdd(&cur[c], 1);
  cinfo[slot] = (c << 16) | n;
  int t = atomicAdd(&vdeg[n], 1);
  if (t < MAXVDEG) vlist[n * MAXVDEG + t] = slot;
}

// ---------------- 16-QAM constellation (fp64 for TX symbol) ----------------
__device__ __forceinline__ void qam_point(int p, double& re, double& im) {
  const double s = 0.31622776601683794;  // 1/sqrt(10)
  int b0 = (p >> 3) & 1, b1 = (p >> 2) & 1, b2 = (p >> 1) & 1, b3 = p & 1;
  re = (double)((1 - 2 * b0) * (2 - (1 - 2 * b2))) * s;
  im = (double)((1 - 2 * b1) * (2 - (1 - 2 * b3))) * s;
}

// ---------------- channel + LMMSE + max-log LLR --------------------------
// fp64 channel/Cholesky/solve with scalarized lower-triangular L (the 4x4
// full arrays at round 4/5 forced VGPR=84 + spills); fp32 demap (reference
// is fp32 there). Output layout Lch3[bt][pair][node][2] so the BP kernel
// streams contiguous float2 per codeword-pair.
__global__ void __launch_bounds__(256, 1)
k_lmmse(const float* __restrict__ h_re, const float* __restrict__ h_im,
        const float* __restrict__ n_re, const float* __restrict__ n_im,
        const float* __restrict__ ebno, const int* __restrict__ symidx2,
        float* __restrict__ Lch3, int T, int ncw) {
  int t = blockIdx.x * blockDim.x + threadIdx.x;
  if (t >= T) return;
  int bt = t / NSYM, s = t - bt * NSYM;

  double no = 1.0 / (pow(10.0, (double)ebno[0] * 0.1) * 2.0);  // BPS*RATE = 2
  const double is2 = 0.7071067811865475244;                     // 1/sqrt(2)

  double Hr[4][4], Hi[4][4];
  {
    const float4* hr4 = (const float4*)h_re;
    const float4* hi4 = (const float4*)h_im;
    #pragma unroll
    for (int i = 0; i < 4; ++i) {
      float4 a = hr4[t * 4 + i], c = hi4[t * 4 + i];
      Hr[i][0] = (double)a.x * is2; Hr[i][1] = (double)a.y * is2;
      Hr[i][2] = (double)a.z * is2; Hr[i][3] = (double)a.w * is2;
      Hi[i][0] = (double)c.x * is2; Hi[i][1] = (double)c.y * is2;
      Hi[i][2] = (double)c.z * is2; Hi[i][3] = (double)c.w * is2;
    }
  }

  double xr[4], xi[4];
  {
    int4 ss = ((const int4*)symidx2)[bt * NSYM + s];
    qam_point(ss.x, xr[0], xi[0]);
    qam_point(ss.y, xr[1], xi[1]);
    qam_point(ss.z, xr[2], xi[2]);
    qam_point(ss.w, xr[3], xi[3]);
  }

  // y = H x + w
  double sq = sqrt(no * 0.5);
  double yr[4], yi[4];
  {
    float4 wr = ((const float4*)n_re)[t];
    float4 wi = ((const float4*)n_im)[t];
    float wrv[4] = {wr.x, wr.y, wr.z, wr.w};
    float wiv[4] = {wi.x, wi.y, wi.z, wi.w};
    #pragma unroll
    for (int i = 0; i < 4; ++i) {
      double ar = (double)wrv[i] * sq;
      double ai = (double)wiv[i] * sq;
      #pragma unroll
      for (int j = 0; j < 4; ++j) {
        ar += Hr[i][j] * xr[j] - Hi[i][j] * xi[j];
        ai += Hr[i][j] * xi[j] + Hi[i][j] * xr[j];
      }
      yr[i] = ar; yi[i] = ai;
    }
  }

  // A = H H^H + no I, lower triangle, directly into scalars
  auto dotc = [&](int i, int j, double& ar, double& ai) {
    double r = 0.0, m = 0.0;
    #pragma unroll
    for (int k = 0; k < 4; ++k) {
      r += Hr[i][k] * Hr[j][k] + Hi[i][k] * Hi[j][k];
      m += Hi[i][k] * Hr[j][k] - Hr[i][k] * Hi[j][k];
    }
    ar = r; ai = m;
  };
  double a00, a11, a22, a33, dum;
  double a10r, a10i, a20r, a20i, a21r, a21i, a30r, a30i, a31r, a31i, a32r, a32i;
  dotc(0, 0, a00, dum);  a00 += no;
  dotc(1, 0, a10r, a10i);
  dotc(1, 1, a11, dum);  a11 += no;
  dotc(2, 0, a20r, a20i);
  dotc(2, 1, a21r, a21i);
  dotc(2, 2, a22, dum);  a22 += no;
  dotc(3, 0, a30r, a30i);
  dotc(3, 1, a31r, a31i);
  dotc(3, 2, a32r, a32i);
  dotc(3, 3, a33, dum);  a33 += no;

  // Cholesky A = L L^H (scalarized)
  double L00 = sqrt(a00);
  double i00 = 1.0 / L00;
  double L10r = a10r * i00, L10i = a10i * i00;
  double L20r = a20r * i00, L20i = a20i * i00;
  double L30r = a30r * i00, L30i = a30i * i00;
  double L11 = sqrt(a11 - (L10r * L10r + L10i * L10i));
  double i11 = 1.0 / L11;
  double L21r = (a21r - (L20r * L10r + L20i * L10i)) * i11;
  double L21i = (a21i - (L20i * L10r - L20r * L10i)) * i11;
  double L31r = (a31r - (L30r * L10r + L30i * L10i)) * i11;
  double L31i = (a31i - (L30i * L10r - L30r * L10i)) * i11;
  double L22 = sqrt(a22 - (L20r * L20r + L20i * L20i) - (L21r * L21r + L21i * L21i));
  double i22 = 1.0 / L22;
  double L32r = (a32r - (L30r * L20r + L30i * L20i) - (L31r * L21r + L31i * L21i)) * i22;
  double L32i = (a32i - (L30i * L20r - L30r * L20i) - (L31i * L21r - L31r * L21i)) * i22;
  double L33 = sqrt(a33 - (L30r * L30r + L30i * L30i) - (L31r * L31r + L31i * L31i)
                        - (L32r * L32r + L32i * L32i));
  double i33 = 1.0 / L33;

  // forward solve: U = L^{-1} H (in place on H), v = L^{-1} y (in place on y)
  #pragma unroll
  for (int j = 0; j < 4; ++j) {
    double u0r = Hr[0][j] * i00,               u0i = Hi[0][j] * i00;
    double u1r = (Hr[1][j] - (L10r * u0r - L10i * u0i)) * i11;
    double u1i = (Hi[1][j] - (L10r * u0i + L10i * u0r)) * i11;
    double u2r = (Hr[2][j] - (L20r * u0r - L20i * u0i) - (L21r * u1r - L21i * u1i)) * i22;
    double u2i = (Hi[2][j] - (L20r * u0i + L20i * u0r) - (L21r * u1i + L21i * u1r)) * i22;
    double u3r = (Hr[3][j] - (L30r * u0r - L30i * u0i) - (L31r * u1r - L31i * u1i)
                           - (L32r * u2r - L32i * u2i)) * i33;
    double u3i = (Hi[3][j] - (L30r * u0i + L30i * u0r) - (L31r * u1i + L31i * u1r)
                           - (L32r * u2i + L32i * u2r)) * i33;
    Hr[0][j] = u0r; Hi[0][j] = u0i; Hr[1][j] = u1r; Hi[1][j] = u1i;
    Hr[2][j] = u2r; Hi[2][j] = u2i; Hr[3][j] = u3r; Hi[3][j] = u3i;
  }
  {
    double v0r = yr[0] * i00,               v0i = yi[0] * i00;
    double v1r = (yr[1] - (L10r * v0r - L10i * v0i)) * i11;
    double v1i = (yi[1] - (L10r * v0i + L10i * v0r)) * i11;
    double v2r = (yr[2] - (L20r * v0r - L20i * v0i) - (L21r * v1r - L21i * v1i)) * i22;
    double v2i = (yi[2] - (L20r * v0i + L20i * v0r) - (L21r * v1i + L21i * v1r)) * i22;
    double v3r = (yr[3] - (L30r * v0r - L30i * v0i) - (L31r * v1r - L31i * v1i)
                        - (L32r * v2r - L32i * v2i)) * i33;
    double v3i = (yi[3] - (L30r * v0i + L30i * v0r) - (L31r * v1i + L31i * v1r)
                        - (L32r * v2i + L32i * v2r)) * i33;
    yr[0] = v0r; yi[0] = v0i; yr[1] = v1r; yi[1] = v1i;
    yr[2] = v2r; yi[2] = v2i; yr[3] = v3r; yi[3] = v3i;
  }

  // fp32 16-QAM table (computed from the same formula)
  const float PRT[16] = { 0.31622776601683794f, 0.31622776601683794f, 0.9486832980505138f, 0.9486832980505138f,
                          0.31622776601683794f, 0.31622776601683794f, 0.9486832980505138f, 0.9486832980505138f,
                         -0.31622776601683794f,-0.31622776601683794f,-0.9486832980505138f,-0.9486832980505138f,
                         -0.31622776601683794f,-0.31622776601683794f,-0.9486832980505138f,-0.9486832980505138f };
  const float PIT[16] = { 0.31622776601683794f, 0.9486832980505138f, 0.31622776601683794f, 0.9486832980505138f,
                         -0.31622776601683794f,-0.9486832980505138f,-0.31622776601683794f,-0.9486832980505138f,
                          0.31622776601683794f, 0.9486832980505138f, 0.31622776601683794f, 0.9486832980505138f,
                         -0.31622776601683794f,-0.9486832980505138f,-0.31622776601683794f,-0.9486832980505138f };

  float llr[4][4];  // [bit k][ue j]
  #pragma unroll
  for (int j = 0; j < 4; ++j) {
    double dj = 0.0, rr = 0.0, ri = 0.0;
    #pragma unroll
    for (int i = 0; i < 4; ++i) {
      dj += Hr[i][j] * Hr[i][j] + Hi[i][j] * Hi[i][j];
      rr += Hr[i][j] * yr[i] + Hi[i][j] * yi[i];
      ri += Hr[i][j] * yi[i] - Hi[i][j] * yr[i];
    }
    float xhr = (float)(rr / dj), xhi = (float)(ri / dj);
    float inoe = (float)(1.0 / fmax(1.0 / dj - 1.0, 1e-12));

    float m0[4] = {-1e30f, -1e30f, -1e30f, -1e30f};
    float m1[4] = {-1e30f, -1e30f, -1e30f, -1e30f};
    #pragma unroll
    for (int p = 0; p < 16; ++p) {
      float dr = xhr - PRT[p], di = xhi - PIT[p];
      float met = -(dr * dr + di * di) * inoe;
      #pragma unroll
      for (int k = 0; k < 4; ++k) {
        if ((p >> (3 - k)) & 1) m1[k] = fmaxf(m1[k], met);
        else                    m0[k] = fmaxf(m0[k], met);
      }
    }
    #pragma unroll
    for (int k = 0; k < 4; ++k) llr[k][j] = m0[k] - m1[k];
  }

  // store: plane 0 = ue{0,1}, plane 1 = ue{2,3}, contiguous float2 per node
  float2* pl0 = (float2*)(Lch3 + (size_t)bt * (NNODES * 4));
  float2* pl1 = pl0 + NNODES;
  #pragma unroll
  for (int k = 0; k < 4; ++k) {
    int node = 4 * s + k;
    pl0[node] = make_float2(llr[k][0], llr[k][1]);
    pl1[node] = make_float2(llr[k][2], llr[k][3]);
  }
}

// ---------------- fused LDS-resident BP decoder, 2 codewords / block --------
__device__ __forceinline__ float tanh_half(float m) {
  // tanh(clip(m*0.5, -9.9, 9.9)) with the reference's 1e-7 magnitude floor
  float mc = fminf(fmaxf(m, -19.8f), 19.8f);
  float e = __expf(mc);
  float t = 1.0f - __fdividef(2.0f, e + 1.0f);
  return (t >= 0.0f) ? fmaxf(t, 1e-7f) : fminf(t, -1e-7f);
}

__device__ __forceinline__ float atanh2c(float P, float t) {
  float r = __fdividef(P, t);
  r = fminf(fmaxf(r, -0.999999f), 0.999999f);
  return __logf(__fdividef(1.0f + r, 1.0f - r));
}

// One block = one codeword PAIR (same Tanner graph). Graph indices cached in
// registers once; all passes are fixed-trip unrolled loops; messages float2.
__global__ void __launch_bounds__(256) k_bp(const float* __restrict__ Lch3,
                                            const int* __restrict__ vlist,
                                            const int* __restrict__ coff,
                                            const int* __restrict__ cinfo,
                                            float* __restrict__ out, int E, int ncw) {
  __shared__ float2 sL[NNODES];
  __shared__ float2 sV[NNODES];
  __shared__ float2 sC[EMAX];
  __shared__ float2 sT[EMAX];
  __shared__ float2 sP[MM];

  int tid = threadIdx.x;
  int pairId = blockIdx.x;  // = bt*2 + plane; codewords 2*pairId, 2*pairId+1

  const float2* src = (const float2*)(Lch3 + (size_t)pairId * (NNODES * 2));
  #pragma unroll
  for (int i = 0; i < 4; ++i) {
    int n = tid + TB * i;
    if (n < NNODES) sL[n] = src[n];
  }
  #pragma unroll
  for (int k = 0; k < 8; ++k)
    sC[tid + TB * k] = make_float2(0.0f, 0.0f);

  // ---- register caches (loaded once, used every iteration) ----
  int evn[8], epc[8]; bool eok[8];
  #pragma unroll
  for (int k = 0; k < 8; ++k) {
    int e = tid + TB * k;
    eok[k] = e < E;
    int info = eok[k] ? cinfo[e] : 0;
    evn[k] = info & 0xffff;   // var node of edge
    epc[k] = info >> 16;      // check of edge
  }
  int vs0[4], vs1[4], vs2[4]; bool nok[4], d3[4];
  #pragma unroll
  for (int i = 0; i < 4; ++i) {
    int n = tid + TB * i;
    nok[i] = n < NNODES;
    d3[i]  = n < KK;          // info nodes: degree 3; parity: degree 1
    int s0 = 0, s1 = 0, s2 = 0;
    if (nok[i]) {
      s0 = vlist[n * MAXVDEG];
      s1 = d3[i] ? vlist[n * MAXVDEG + 1] : s0;
      s2 = d3[i] ? vlist[n * MAXVDEG + 2] : s0;
    }
    vs0[i] = s0; vs1[i] = s1; vs2[i] = s2;
  }
  int beg0 = coff[tid], end0 = coff[tid + 1];
  bool c1ok = (tid + TB) < MM;
  int beg1 = c1ok ? coff[tid + TB] : 0;
  int end1 = c1ok ? coff[tid + TB + 1] : 0;
  __syncthreads();

  for (int it = 0; it < NITERS; ++it) {
    // vtot (node-parallel; uniform via fixed degrees)
    #pragma unroll
    for (int i = 0; i < 4; ++i) {
      if (nok[i]) {
        int n = tid + TB * i;
        float2 a = sL[n];
        float2 c0 = sC[vs0[i]], c1 = sC[vs1[i]], c2 = sC[vs2[i]];
        float ax = a.x + c0.x, ay = a.y + c0.y;
        if (d3[i]) { ax += c1.x + c2.x; ay += c1.y + c2.y; }
        sV[n] = make_float2(ax, ay);
      }
    }
    __syncthreads();
    // tanh of v2c (edge-parallel, unrolled)
    #pragma unroll
    for (int k = 0; k < 8; ++k) {
      if (eok[k]) {
        int e = tid + TB * k;
        float2 v = sV[evn[k]];
        float2 c = sC[e];
        sT[e] = make_float2(tanh_half(v.x - c.x), tanh_half(v.y - c.y));
      }
    }
    __syncthreads();
    // per-check products (multiplies only under divergence)
    {
      float px = 1.0f, py = 1.0f;
      for (int e = beg0; e < end0; ++e) { float2 tt = sT[e]; px *= tt.x; py *= tt.y; }
      sP[tid] = make_float2(px, py);
      if (c1ok) {
        float qx = 1.0f, qy = 1.0f;
        for (int e = beg1; e < end1; ++e) { float2 tt = sT[e]; qx *= tt.x; qy *= tt.y; }
        sP[tid + TB] = make_float2(qx, qy);
      }
    }
    __syncthreads();
    // c2v update (edge-parallel, unrolled; all transcendentals uniform)
    #pragma unroll
    for (int k = 0; k < 8; ++k) {
      if (eok[k]) {
        int e = tid + TB * k;
        float2 P = sP[epc[k]];
        float2 tt = sT[e];
        sC[e] = make_float2(atanh2c(P.x, tt.x), atanh2c(P.y, tt.y));
      }
    }
    __syncthreads();
  }

  // decide info bits for both codewords
  int cw0 = pairId * 2;
  float* o0 = out + (size_t)ncw * KK + (size_t)cw0 * KK;
  float* o1 = o0 + KK;
  #pragma unroll
  for (int i = 0; i < 2; ++i) {
    int n = tid + TB * i;
    if (n < KK) {
      float2 a = sL[n];
      float2 c0 = sC[vs0[i]], c1 = sC[vs1[i]], c2 = sC[vs2[i]];
      float ax = a.x + c0.x + c1.x + c2.x;
      float ay = a.y + c0.y + c1.y + c2.y;
      o0[n] = (ax < 0.0f) ? 1.0f : 0.0f;
      o1[n] = (ay < 0.0f) ? 1.0f : 0.0f;
    }
  }
}

// ---------------- launcher ----------------
extern "C" void kernel_launch(void* const* d_in, const int* in_sizes, int n_in,
                              void* d_out, int out_size, void* d_ws, size_t ws_size,
                              hipStream_t stream) {
  const float* ebno = (const float*)d_in[1];
  const int*   b    = (const int*)d_in[2];
  const int*   P    = (const int*)d_in[3];
  const int*   cn   = (const int*)d_in[4];
  const int*   vn   = (const int*)d_in[5];
  const float* h_re = (const float*)d_in[6];
  const float* h_im = (const float*)d_in[7];
  const float* nre  = (const float*)d_in[8];
  const float* nim  = (const float*)d_in[9];
  float* out = (float*)d_out;

  int E     = in_sizes[4];
  int batch = in_sizes[2] / (4 * KK);
  int ncw   = batch * 4;
  int T     = batch * NSYM;

  char* ws = (char*)d_ws;
  size_t off = 0;
  auto alloc = [&](size_t bytes) -> void* {
    void* p = ws + off;
    off += (bytes + 255) & ~(size_t)255;
    return p;
  };
  float*    Lch3   = (float*)alloc((size_t)NNODES * ncw * 4);
  int*      symidx = (int*)alloc((size_t)ncw * NSYM * 4);
  unsigned* Ppack  = (unsigned*)alloc((size_t)MM * 16 * 4);
  unsigned* bpack  = (unsigned*)alloc((size_t)ncw * 16 * 4);
  int*      cdeg   = (int*)alloc((size_t)MM * 4);
  int*      coff   = (int*)alloc((size_t)(MM + 1) * 4);
  int*      cur    = (int*)alloc((size_t)MM * 4);
  int*      cinfo  = (int*)alloc((size_t)EMAX * 4);
  int*      vdeg   = (int*)alloc((size_t)NNODES * 4);
  int*      vlist  = (int*)alloc((size_t)NNODES * MAXVDEG * 4);
  (void)ws_size; (void)n_in; (void)out_size;

  const int tb = 256;
  hipMemsetAsync(cdeg, 0, (size_t)MM * 4, stream);
  hipMemsetAsync(vdeg, 0, (size_t)NNODES * 4, stream);

  k_pack_P<<<dim3((MM * 16 + tb - 1) / tb), dim3(tb), 0, stream>>>(P, Ppack);
  k_pack_b<<<dim3((ncw * 16 + tb - 1) / tb), dim3(tb), 0, stream>>>(b, bpack, ncw);
  k_sym<<<dim3((ncw * NSYM + tb - 1) / tb), dim3(tb), 0, stream>>>(bpack, Ppack, symidx, ncw);
  k_bf<<<dim3((ncw * KK + tb - 1) / tb), dim3(tb), 0, stream>>>(b, out, ncw * KK);

  k_count<<<dim3((E + tb - 1) / tb), dim3(tb), 0, stream>>>(cn, E, cdeg);
  k_scan<<<dim3(1), dim3(512), 0, stream>>>(cdeg, coff, cur);
  k_fill2<<<dim3((E + tb - 1) / tb), dim3(tb), 0, stream>>>(cn, vn, E, cur, cinfo, vdeg, vlist);

  k_lmmse<<<dim3((T + tb - 1) / tb), dim3(tb), 0, stream>>>(h_re, h_im, nre, nim, ebno, symidx, Lch3, T, ncw);

  k_bp<<<dim3(ncw / 2), dim3(tb), 0, stream>>>(Lch3, vlist, coff, cinfo, out, E, ncw);
}